// Round 4
// baseline (189.919 us; speedup 1.0000x reference)
//
#include <hip/hip_runtime.h>

typedef short bf16x8 __attribute__((ext_vector_type(8)));
typedef float f32x4 __attribute__((ext_vector_type(4)));

#define MFMA16(a, b, c) __builtin_amdgcn_mfma_f32_16x16x32_bf16((a), (b), (c), 0, 0, 0)

#define GLOAD_LDS16(g, l)                                              \
  __builtin_amdgcn_global_load_lds(                                    \
      (const __attribute__((address_space(1))) unsigned int*)(g),      \
      (__attribute__((address_space(3))) unsigned int*)(l), 16, 0, 0)

__device__ __forceinline__ unsigned short f2b(float f) {
  union { float f; unsigned int u; } x; x.f = f;
  unsigned int r = x.u + 0x7FFFu + ((x.u >> 16) & 1u);
  return (unsigned short)(r >> 16);
}
__device__ __forceinline__ float b2f(unsigned short h) {
  union { unsigned int u; float f; } x; x.u = ((unsigned int)h) << 16;
  return x.f;
}
__device__ __forceinline__ unsigned int cvtpk(float lo, float hi) {
  unsigned int r;
  asm("v_cvt_pk_bf16_f32 %0, %1, %2" : "=v"(r) : "v"(lo), "v"(hi));
  return r;
}

// ---------------- weight transpose+convert: W[512][512] f32 -> Wt[512n][512k] bf16
__global__ __launch_bounds__(256) void wtrans_kernel(
    const float* __restrict__ Wq, const float* __restrict__ Wk,
    const float* __restrict__ Wv, const float* __restrict__ Wo,
    short* __restrict__ Wt) {
  __shared__ float tile[64][65];
  const int z = blockIdx.z;
  const float* W = (z == 0) ? Wq : (z == 1) ? Wk : (z == 2) ? Wv : Wo;
  const int k0 = blockIdx.x * 64, n0 = blockIdx.y * 64;
  const int t = threadIdx.x;
  const int r = t >> 4, cc = (t & 15) * 4;
#pragma unroll
  for (int it = 0; it < 4; ++it) {
    int row = r + it * 16;
    const float4 v = *(const float4*)(W + (k0 + row) * 512 + n0 + cc);
    tile[row][cc + 0] = v.x; tile[row][cc + 1] = v.y;
    tile[row][cc + 2] = v.z; tile[row][cc + 3] = v.w;
  }
  __syncthreads();
  short* out = Wt + z * (512 * 512);
#pragma unroll
  for (int it = 0; it < 4; ++it) {
    int nrow = r + it * 16;
    unsigned int u0 = cvtpk(tile[cc + 0][nrow], tile[cc + 1][nrow]);
    unsigned int u1 = cvtpk(tile[cc + 2][nrow], tile[cc + 3][nrow]);
    uint2 uv; uv.x = u0; uv.y = u1;
    *(uint2*)(out + (n0 + nrow) * 512 + k0 + cc) = uv;
  }
}

// ---------------- convert Q,K f32 -> bf16
__global__ __launch_bounds__(256) void cvt_kernel(
    const float* __restrict__ Q, const float* __restrict__ K,
    short* __restrict__ Qb, short* __restrict__ Kb) {
  const float* src = blockIdx.y ? K : Q;
  short* dst = blockIdx.y ? Kb : Qb;
  int i = (blockIdx.x * 256 + threadIdx.x) * 8;
  float4 v0 = *(const float4*)(src + i);
  float4 v1 = *(const float4*)(src + i + 4);
  uint2 a, b;
  a.x = cvtpk(v0.x, v0.y); a.y = cvtpk(v0.z, v0.w);
  b.x = cvtpk(v1.x, v1.y); b.y = cvtpk(v1.z, v1.w);
  *(uint2*)(dst + i) = a;
  *(uint2*)(dst + i + 4) = b;
}

// ---------------- m97-style GEMM mainloop: 128x128 tile, BK=64, gload_lds staging
__device__ __forceinline__ void gemm_bf16_core(
    const short* __restrict__ A, const short* __restrict__ Wt,
    short* Al, short* Bl, int m0, int t, f32x4 acc[4][4]) {
  const int lane = t & 63, w = t >> 6;
  const int c = lane & 15, g = lane >> 4;
  const int wr = w >> 1, wc = w & 1;
  const int lr = lane >> 3, lc = (lane & 7) * 8;
  for (int kt = 0; kt < 8; ++kt) {
#pragma unroll
    for (int it = 0; it < 4; ++it) {
      int row = w * 32 + it * 8;
      GLOAD_LDS16(A + (size_t)(m0 + row + lr) * 512 + kt * 64 + lc, Al + row * 64);
      GLOAD_LDS16(Wt + (size_t)(row + lr) * 512 + kt * 64 + lc, Bl + row * 64);
    }
    __syncthreads();
#pragma unroll
    for (int kc = 0; kc < 2; ++kc) {
      bf16x8 af[4], bfr[4];
#pragma unroll
      for (int mi = 0; mi < 4; ++mi)
        af[mi] = *(const bf16x8*)(Al + (wr * 64 + mi * 16 + c) * 64 + kc * 32 + 8 * g);
#pragma unroll
      for (int ni = 0; ni < 4; ++ni)
        bfr[ni] = *(const bf16x8*)(Bl + (wc * 64 + ni * 16 + c) * 64 + kc * 32 + 8 * g);
#pragma unroll
      for (int mi = 0; mi < 4; ++mi)
#pragma unroll
        for (int ni = 0; ni < 4; ++ni)
          acc[mi][ni] = MFMA16(af[mi], bfr[ni], acc[mi][ni]);
    }
    __syncthreads();
  }
}

// ---------------- fused projections
__global__ __launch_bounds__(256) void proj2_kernel(
    const short* __restrict__ Qb, const short* __restrict__ Kb,
    const short* __restrict__ Wt4,
    const float* __restrict__ bq, const float* __restrict__ bk, const float* __restrict__ bv,
    const float* __restrict__ maskf,
    short* __restrict__ Qp, short* __restrict__ Kp, short* __restrict__ Vt) {
  __shared__ short Al[128 * 64];
  __shared__ short Bl[128 * 64];
  const int by = blockIdx.y;
  const int m0 = blockIdx.x * 128;
  const int t = threadIdx.x;
  const short* A;
  const short* Wt;
  const float* bias;
  int nbase;
  if (by < 4) { A = Qb; nbase = by * 128; Wt = Wt4 + nbase * 512; bias = bq; }
  else if (by < 8) { A = Kb; nbase = (by - 4) * 128; Wt = Wt4 + 262144 + nbase * 512; bias = bk; }
  else { A = Kb; nbase = (by - 8) * 128; Wt = Wt4 + 524288 + nbase * 512; bias = bv; }

  const f32x4 zz = {0.f, 0.f, 0.f, 0.f};
  f32x4 acc[4][4];
#pragma unroll
  for (int mi = 0; mi < 4; ++mi)
#pragma unroll
    for (int ni = 0; ni < 4; ++ni) acc[mi][ni] = zz;
  gemm_bf16_core(A, Wt, Al, Bl, m0, t, acc);

  const int lane = t & 63, w = t >> 6;
  const int c = lane & 15, g = lane >> 4;
  const int wr = w >> 1, wc = w & 1;
  float mk[4][4];
#pragma unroll
  for (int mi = 0; mi < 4; ++mi) {
    int mbase = m0 + wr * 64 + mi * 16 + 4 * g;
#pragma unroll
    for (int i = 0; i < 4; ++i) mk[mi][i] = maskf[mbase + i];
  }
  if (by < 8) {
    short* out = (by < 4) ? Qp : Kp;
#pragma unroll
    for (int ni = 0; ni < 4; ++ni) {
      int n = nbase + wc * 64 + ni * 16 + c;
      float bval = bias[n];
#pragma unroll
      for (int mi = 0; mi < 4; ++mi) {
        int mbase = m0 + wr * 64 + mi * 16 + 4 * g;
#pragma unroll
        for (int i = 0; i < 4; ++i)
          out[(size_t)(mbase + i) * 512 + n] = (short)f2b((acc[mi][ni][i] + bval) * mk[mi][i]);
      }
    }
  } else {
#pragma unroll
    for (int ni = 0; ni < 4; ++ni) {
      int d = nbase + wc * 64 + ni * 16 + c;
      int h = d >> 6, dd = d & 63;
      float bval = bias[d];
#pragma unroll
      for (int mi = 0; mi < 4; ++mi) {
        int mbase = m0 + wr * 64 + mi * 16 + 4 * g;
        int bi = mbase >> 10, seq0 = mbase & 1023;
        unsigned int u0 = cvtpk((acc[mi][ni][0] + bval) * mk[mi][0],
                                (acc[mi][ni][1] + bval) * mk[mi][1]);
        unsigned int u1 = cvtpk((acc[mi][ni][2] + bval) * mk[mi][2],
                                (acc[mi][ni][3] + bval) * mk[mi][3]);
        uint2 uv; uv.x = u0; uv.y = u1;
        *(uint2*)(Vt + ((size_t)(bi * 8 + h) * 64 + dd) * 1024 + seq0) = uv;
      }
    }
  }
}

// ---------------- flash attention per (h,b): BARRIER-FREE, per-lane global K/V frags
__global__ __launch_bounds__(256, 3) void attn_kernel(
    const short* __restrict__ Qp, const short* __restrict__ Kp,
    const short* __restrict__ Vt, const float* __restrict__ mask,
    float* __restrict__ Ob, short* __restrict__ Obb) {
  __shared__ short Pl[4][16][64];  // 8 KB, per-wave, XOR-swizzled; no barriers anywhere
  const int t = threadIdx.x, lane = t & 63, w = t >> 6;
  const int c = lane & 15, g = lane >> 4;
  // XCD-aware swizzle: 16 consecutive logical blocks (one (b,h)) per XCD chunk
  const int hw = blockIdx.x;
  const int L = (hw & 7) * 128 + (hw >> 3);
  const int qt = L & 15, hb = L >> 4;
  const int b = hb & 7, h = hb >> 3;
  const int n0 = qt * 64;
  const float scale2 = 0.06375870724f;  // log2(e)/sqrt(512)
  const float DEFER = 125.0f;           // ~8/scale2

  const short* Kg = Kp + (size_t)(b * 1024) * 512 + h * 64;        // [kv][512] slice
  const short* Vg = Vt + (size_t)((b * 8 + h) * 64) * 1024;        // [d][1024] slice
  const float* Mg = mask + b * 1024;
  const int swc = (c & 7) << 3;  // Pl XOR key (shorts)

  bf16x8 qf0, qf1;
  {
    const short* qptr = Qp + ((size_t)(b * 1024 + n0 + w * 16 + c) * 512 + h * 64 + 8 * g);
    qf0 = *(const bf16x8*)qptr;
    qf1 = *(const bf16x8*)(qptr + 32);
  }

  float runmax = -1e30f, lrun = 0.f;
  const f32x4 zz = {0.f, 0.f, 0.f, 0.f};
  f32x4 o[4];
  o[0] = zz; o[1] = zz; o[2] = zz; o[3] = zz;

  for (int kvt = 0; kvt < 16; ++kvt) {
    const short* kt_ = Kg + (size_t)kvt * 64 * 512;
    const short* vt_ = Vg + kvt * 64;

    // mask (L1-resident after tile 0; 16 lanes share each address)
    float4 m2[4];
#pragma unroll
    for (int j = 0; j < 4; ++j)
      m2[j] = *(const float4*)(Mg + kvt * 64 + 16 * j + 4 * g);

    // K fragments straight from global (identical addresses across the 4 waves -> L1 reuse)
    bf16x8 af[4][2];
#pragma unroll
    for (int j = 0; j < 4; ++j) {
#pragma unroll
      for (int kc = 0; kc < 2; ++kc)
        af[j][kc] = *(const bf16x8*)(kt_ + (size_t)(16 * j + c) * 512 + kc * 32 + 8 * g);
    }

    // QK^T swapped: lane holds S^T[kv=16j+4g+i][q=c]
    f32x4 s[4];
#pragma unroll
    for (int j = 0; j < 4; ++j) {
      f32x4 sj = zz;
      sj = MFMA16(af[j][0], qf0, sj);
      sj = MFMA16(af[j][1], qf1, sj);
      s[j] = sj;
    }

    // V fragments issue here; softmax below covers their latency
    bf16x8 vf[2][4];
#pragma unroll
    for (int ks = 0; ks < 2; ++ks) {
#pragma unroll
      for (int nb = 0; nb < 4; ++nb)
        vf[ks][nb] = *(const bf16x8*)(vt_ + (size_t)(16 * nb + c) * 1024 + ks * 32 + 8 * g);
    }

    // row max (max3-friendly trees)
    float ma = fmaxf(fmaxf(s[0][0], s[0][1]), fmaxf(fmaxf(s[0][2], s[0][3]), s[1][0]));
    float mb = fmaxf(fmaxf(s[1][1], s[1][2]), fmaxf(fmaxf(s[1][3], s[2][0]), s[2][1]));
    float mc = fmaxf(fmaxf(s[2][2], s[2][3]), fmaxf(fmaxf(s[3][0], s[3][1]), s[3][2]));
    float mt = fmaxf(fmaxf(ma, mb), fmaxf(mc, s[3][3]));
    mt = fmaxf(mt, __shfl_xor(mt, 16));
    mt = fmaxf(mt, __shfl_xor(mt, 32));

    // T13 defer-rescale
    if (!__all(mt <= runmax + DEFER)) {
      float newmax = fmaxf(runmax, mt);
      float factor = exp2f(scale2 * (runmax - newmax));
      runmax = newmax;
      lrun *= factor;
#pragma unroll
      for (int i = 0; i < 4; ++i) {
        float fi = __shfl(factor, 4 * g + i);
        o[0][i] *= fi; o[1][i] *= fi; o[2][i] *= fi; o[3][i] *= fi;
      }
    }

    const float negb = -scale2 * runmax;
    float tsum = 0.f;
#pragma unroll
    for (int j = 0; j < 4; ++j) {
      float p0 = exp2f(fmaf(scale2, s[j][0], negb)) * m2[j].x;
      float p1 = exp2f(fmaf(scale2, s[j][1], negb)) * m2[j].y;
      float p2 = exp2f(fmaf(scale2, s[j][2], negb)) * m2[j].z;
      float p3 = exp2f(fmaf(scale2, s[j][3], negb)) * m2[j].w;
      tsum += (p0 + p1) + (p2 + p3);
      uint2 pw; pw.x = cvtpk(p0, p1); pw.y = cvtpk(p2, p3);
      *(uint2*)(&Pl[w][c][(16 * j + 4 * g) ^ swc]) = pw;
    }
    tsum += __shfl_xor(tsum, 16);
    tsum += __shfl_xor(tsum, 32);
    lrun += tsum;

#pragma unroll
    for (int ks = 0; ks < 2; ++ks) {
      bf16x8 pa = *(const bf16x8*)(&Pl[w][c][(ks * 32 + 8 * g) ^ swc]);
#pragma unroll
      for (int nb = 0; nb < 4; ++nb)
        o[nb] = MFMA16(pa, vf[ks][nb], o[nb]);
    }
  }

  float lr[4], mk1[4];
#pragma unroll
  for (int i = 0; i < 4; ++i) {
    lr[i] = __shfl(lrun, 4 * g + i);
    mk1[i] = Mg[n0 + w * 16 + 4 * g + i];
  }
#pragma unroll
  for (int nb = 0; nb < 4; ++nb) {
    int colg = h * 64 + 16 * nb + c;
#pragma unroll
    for (int i = 0; i < 4; ++i) {
      int row = n0 + w * 16 + 4 * g + i;
      float att = o[nb][i] / (lr[i] + 1e-16f);
      float qv = b2f(*(const unsigned short*)(Qp + (size_t)(b * 1024 + row) * 512 + colg));
      float res = qv + mk1[i] * att;
      size_t off = (size_t)(b * 1024 + row) * 512 + colg;
      Ob[off] = res;
      Obb[off] = (short)f2b(res);
    }
  }
}

// ---------------- final: out = Ob + relu((Obb@Wo + bo) * mask)
__global__ __launch_bounds__(256) void final2_kernel(
    const short* __restrict__ Obb, const float* __restrict__ Obf,
    const short* __restrict__ Wto, const float* __restrict__ bo,
    const float* __restrict__ maskf, float* __restrict__ out) {
  __shared__ short Al[128 * 64];
  __shared__ short Bl[128 * 64];
  const int m0 = blockIdx.x * 128, n0 = blockIdx.y * 128;
  const int t = threadIdx.x;
  const f32x4 zz = {0.f, 0.f, 0.f, 0.f};
  f32x4 acc[4][4];
#pragma unroll
  for (int mi = 0; mi < 4; ++mi)
#pragma unroll
    for (int ni = 0; ni < 4; ++ni) acc[mi][ni] = zz;
  gemm_bf16_core(Obb, Wto + n0 * 512, Al, Bl, m0, t, acc);

  const int lane = t & 63, w = t >> 6;
  const int c = lane & 15, g = lane >> 4;
  const int wr = w >> 1, wc = w & 1;
  float mk[4][4];
#pragma unroll
  for (int mi = 0; mi < 4; ++mi) {
    int mbase = m0 + wr * 64 + mi * 16 + 4 * g;
#pragma unroll
    for (int i = 0; i < 4; ++i) mk[mi][i] = maskf[mbase + i];
  }
#pragma unroll
  for (int ni = 0; ni < 4; ++ni) {
    int n = n0 + wc * 64 + ni * 16 + c;
    float bval = bo[n];
#pragma unroll
    for (int mi = 0; mi < 4; ++mi) {
      int mbase = m0 + wr * 64 + mi * 16 + 4 * g;
#pragma unroll
      for (int i = 0; i < 4; ++i) {
        float v = (acc[mi][ni][i] + bval) * mk[mi][i];
        v = fmaxf(v, 0.f);
        size_t off = (size_t)(mbase + i) * 512 + n;
        out[off] = Obf[off] + v;
      }
    }
  }
}

extern "C" void kernel_launch(void* const* d_in, const int* in_sizes, int n_in,
                              void* d_out, int out_size, void* d_ws, size_t ws_size,
                              hipStream_t stream) {
  (void)in_sizes; (void)n_in; (void)out_size; (void)ws_size;
  const float* Q    = (const float*)d_in[0];
  const float* K    = (const float*)d_in[1];
  const float* mask = (const float*)d_in[2];
  const float* Wq   = (const float*)d_in[3];
  const float* bq   = (const float*)d_in[4];
  const float* Wk   = (const float*)d_in[5];
  const float* bk   = (const float*)d_in[6];
  const float* Wv   = (const float*)d_in[7];
  const float* bv   = (const float*)d_in[8];
  const float* Wo   = (const float*)d_in[9];
  const float* bo   = (const float*)d_in[10];

  char* ws = (char*)d_ws;
  const size_t MB = 1048576;
  short* Wt4 = (short*)ws;                 // 2 MiB: 4x 512x512 bf16
  short* Qb  = (short*)(ws + 2 * MB);      // 8 MiB
  short* Kb  = (short*)(ws + 10 * MB);     // 8 MiB
  short* Qp  = (short*)(ws + 18 * MB);     // 8 MiB
  short* Kp  = (short*)(ws + 26 * MB);     // 8 MiB
  short* Vt  = (short*)(ws + 34 * MB);     // 8 MiB: [B][H][64][1024]
  short* Obb = (short*)(ws + 42 * MB);     // 8 MiB
  float* Ob  = (float*)(ws + 2 * MB);      // 16 MiB (reuses Qb/Kb after proj)
  float* out = (float*)d_out;

  wtrans_kernel<<<dim3(8, 8, 4), 256, 0, stream>>>(Wq, Wk, Wv, Wo, Wt4);
  cvt_kernel<<<dim3(2048, 2), 256, 0, stream>>>(Q, K, Qb, Kb);
  proj2_kernel<<<dim3(64, 12), 256, 0, stream>>>(Qb, Kb, Wt4, bq, bk, bv, mask, Qp, Kp, Vt);
  attn_kernel<<<dim3(1024), 256, 0, stream>>>(Qp, Kp, Vt, mask, Ob, Obb);
  final2_kernel<<<dim3(64, 4), 256, 0, stream>>>(Obb, Ob, Wt4 + 3 * 262144, bo, mask, out);
}

// Round 5
// 101.221 us; speedup vs baseline: 1.8763x; 1.8763x over previous
//
#include <hip/hip_runtime.h>

typedef short bf16x8 __attribute__((ext_vector_type(8)));
typedef float f32x4 __attribute__((ext_vector_type(4)));

#define MFMA16(a, b, c) __builtin_amdgcn_mfma_f32_16x16x32_bf16((a), (b), (c), 0, 0, 0)

#define GLOAD_LDS16(g, l)                                              \
  __builtin_amdgcn_global_load_lds(                                    \
      (const __attribute__((address_space(1))) unsigned int*)(g),      \
      (__attribute__((address_space(3))) unsigned int*)(l), 16, 0, 0)

__device__ __forceinline__ unsigned short f2b(float f) {
  union { float f; unsigned int u; } x; x.f = f;
  unsigned int r = x.u + 0x7FFFu + ((x.u >> 16) & 1u);
  return (unsigned short)(r >> 16);
}
__device__ __forceinline__ float b2f(unsigned short h) {
  union { unsigned int u; float f; } x; x.u = ((unsigned int)h) << 16;
  return x.f;
}
__device__ __forceinline__ unsigned int cvtpk(float lo, float hi) {
  unsigned int r;
  asm("v_cvt_pk_bf16_f32 %0, %1, %2" : "=v"(r) : "v"(lo), "v"(hi));
  return r;
}

// ---------------- weight transpose+convert: W[512][512] f32 -> Wt[512n][512k] bf16
__global__ __launch_bounds__(256) void wtrans_kernel(
    const float* __restrict__ Wq, const float* __restrict__ Wk,
    const float* __restrict__ Wv, const float* __restrict__ Wo,
    short* __restrict__ Wt) {
  __shared__ float tile[64][65];
  const int z = blockIdx.z;
  const float* W = (z == 0) ? Wq : (z == 1) ? Wk : (z == 2) ? Wv : Wo;
  const int k0 = blockIdx.x * 64, n0 = blockIdx.y * 64;
  const int t = threadIdx.x;
  const int r = t >> 4, cc = (t & 15) * 4;
#pragma unroll
  for (int it = 0; it < 4; ++it) {
    int row = r + it * 16;
    const float4 v = *(const float4*)(W + (k0 + row) * 512 + n0 + cc);
    tile[row][cc + 0] = v.x; tile[row][cc + 1] = v.y;
    tile[row][cc + 2] = v.z; tile[row][cc + 3] = v.w;
  }
  __syncthreads();
  short* out = Wt + z * (512 * 512);
#pragma unroll
  for (int it = 0; it < 4; ++it) {
    int nrow = r + it * 16;
    unsigned int u0 = cvtpk(tile[cc + 0][nrow], tile[cc + 1][nrow]);
    unsigned int u1 = cvtpk(tile[cc + 2][nrow], tile[cc + 3][nrow]);
    uint2 uv; uv.x = u0; uv.y = u1;
    *(uint2*)(out + (n0 + nrow) * 512 + k0 + cc) = uv;
  }
}

// ---------------- convert Q,K f32 -> bf16; also build additive logmask ml
__global__ __launch_bounds__(256) void cvt_kernel(
    const float* __restrict__ Q, const float* __restrict__ K,
    const float* __restrict__ mask,
    short* __restrict__ Qb, short* __restrict__ Kb, float* __restrict__ ml) {
  if (blockIdx.y == 0 && blockIdx.x < 4) {
    int i = (blockIdx.x * 256 + threadIdx.x) * 2;  // 4*256*2 = 2048... cover 8192 via 4 per thread
    i *= 4;                                        // 8 elems per thread
    float4 a = *(const float4*)(mask + i);
    float4 bb = *(const float4*)(mask + i + 4);
    float4 ra, rb;
    ra.x = (a.x != 0.f) ? 0.f : -1e30f;
    ra.y = (a.y != 0.f) ? 0.f : -1e30f;
    ra.z = (a.z != 0.f) ? 0.f : -1e30f;
    ra.w = (a.w != 0.f) ? 0.f : -1e30f;
    rb.x = (bb.x != 0.f) ? 0.f : -1e30f;
    rb.y = (bb.y != 0.f) ? 0.f : -1e30f;
    rb.z = (bb.z != 0.f) ? 0.f : -1e30f;
    rb.w = (bb.w != 0.f) ? 0.f : -1e30f;
    *(float4*)(ml + i) = ra;
    *(float4*)(ml + i + 4) = rb;
  }
  const float* src = blockIdx.y ? K : Q;
  short* dst = blockIdx.y ? Kb : Qb;
  int i = (blockIdx.x * 256 + threadIdx.x) * 8;
  float4 v0 = *(const float4*)(src + i);
  float4 v1 = *(const float4*)(src + i + 4);
  uint2 a, b;
  a.x = cvtpk(v0.x, v0.y); a.y = cvtpk(v0.z, v0.w);
  b.x = cvtpk(v1.x, v1.y); b.y = cvtpk(v1.z, v1.w);
  *(uint2*)(dst + i) = a;
  *(uint2*)(dst + i + 4) = b;
}

// ---------------- m97-style GEMM mainloop: 128x128 tile, BK=64, gload_lds staging
__device__ __forceinline__ void gemm_bf16_core(
    const short* __restrict__ A, const short* __restrict__ Wt,
    short* Al, short* Bl, int m0, int t, f32x4 acc[4][4]) {
  const int lane = t & 63, w = t >> 6;
  const int c = lane & 15, g = lane >> 4;
  const int wr = w >> 1, wc = w & 1;
  const int lr = lane >> 3, lc = (lane & 7) * 8;
  for (int kt = 0; kt < 8; ++kt) {
#pragma unroll
    for (int it = 0; it < 4; ++it) {
      int row = w * 32 + it * 8;
      GLOAD_LDS16(A + (size_t)(m0 + row + lr) * 512 + kt * 64 + lc, Al + row * 64);
      GLOAD_LDS16(Wt + (size_t)(row + lr) * 512 + kt * 64 + lc, Bl + row * 64);
    }
    __syncthreads();
#pragma unroll
    for (int kc = 0; kc < 2; ++kc) {
      bf16x8 af[4], bfr[4];
#pragma unroll
      for (int mi = 0; mi < 4; ++mi)
        af[mi] = *(const bf16x8*)(Al + (wr * 64 + mi * 16 + c) * 64 + kc * 32 + 8 * g);
#pragma unroll
      for (int ni = 0; ni < 4; ++ni)
        bfr[ni] = *(const bf16x8*)(Bl + (wc * 64 + ni * 16 + c) * 64 + kc * 32 + 8 * g);
#pragma unroll
      for (int mi = 0; mi < 4; ++mi)
#pragma unroll
        for (int ni = 0; ni < 4; ++ni)
          acc[mi][ni] = MFMA16(af[mi], bfr[ni], acc[mi][ni]);
    }
    __syncthreads();
  }
}

// ---------------- fused projections
__global__ __launch_bounds__(256) void proj2_kernel(
    const short* __restrict__ Qb, const short* __restrict__ Kb,
    const short* __restrict__ Wt4,
    const float* __restrict__ bq, const float* __restrict__ bk, const float* __restrict__ bv,
    const float* __restrict__ maskf,
    short* __restrict__ Qp, short* __restrict__ Kp, short* __restrict__ Vt) {
  __shared__ short Al[128 * 64];
  __shared__ short Bl[128 * 64];
  const int by = blockIdx.y;
  const int m0 = blockIdx.x * 128;
  const int t = threadIdx.x;
  const short* A;
  const short* Wt;
  const float* bias;
  int nbase;
  if (by < 4) { A = Qb; nbase = by * 128; Wt = Wt4 + nbase * 512; bias = bq; }
  else if (by < 8) { A = Kb; nbase = (by - 4) * 128; Wt = Wt4 + 262144 + nbase * 512; bias = bk; }
  else { A = Kb; nbase = (by - 8) * 128; Wt = Wt4 + 524288 + nbase * 512; bias = bv; }

  const f32x4 zz = {0.f, 0.f, 0.f, 0.f};
  f32x4 acc[4][4];
#pragma unroll
  for (int mi = 0; mi < 4; ++mi)
#pragma unroll
    for (int ni = 0; ni < 4; ++ni) acc[mi][ni] = zz;
  gemm_bf16_core(A, Wt, Al, Bl, m0, t, acc);

  const int lane = t & 63, w = t >> 6;
  const int c = lane & 15, g = lane >> 4;
  const int wr = w >> 1, wc = w & 1;
  float mk[4][4];
#pragma unroll
  for (int mi = 0; mi < 4; ++mi) {
    int mbase = m0 + wr * 64 + mi * 16 + 4 * g;
#pragma unroll
    for (int i = 0; i < 4; ++i) mk[mi][i] = maskf[mbase + i];
  }
  if (by < 8) {
    short* out = (by < 4) ? Qp : Kp;
#pragma unroll
    for (int ni = 0; ni < 4; ++ni) {
      int n = nbase + wc * 64 + ni * 16 + c;
      float bval = bias[n];
#pragma unroll
      for (int mi = 0; mi < 4; ++mi) {
        int mbase = m0 + wr * 64 + mi * 16 + 4 * g;
#pragma unroll
        for (int i = 0; i < 4; ++i)
          out[(size_t)(mbase + i) * 512 + n] = (short)f2b((acc[mi][ni][i] + bval) * mk[mi][i]);
      }
    }
  } else {
#pragma unroll
    for (int ni = 0; ni < 4; ++ni) {
      int d = nbase + wc * 64 + ni * 16 + c;
      int h = d >> 6, dd = d & 63;
      float bval = bias[d];
#pragma unroll
      for (int mi = 0; mi < 4; ++mi) {
        int mbase = m0 + wr * 64 + mi * 16 + 4 * g;
        int bi = mbase >> 10, seq0 = mbase & 1023;
        unsigned int u0 = cvtpk((acc[mi][ni][0] + bval) * mk[mi][0],
                                (acc[mi][ni][1] + bval) * mk[mi][1]);
        unsigned int u1 = cvtpk((acc[mi][ni][2] + bval) * mk[mi][2],
                                (acc[mi][ni][3] + bval) * mk[mi][3]);
        uint2 uv; uv.x = u0; uv.y = u1;
        *(uint2*)(Vt + ((size_t)(bi * 8 + h) * 64 + dd) * 1024 + seq0) = uv;
      }
    }
  }
}

// ---------------- flash attention per (h,b): LDS-staged, no-max softmax, MFMA rowsum
__global__ __launch_bounds__(256) void attn_kernel(
    const short* __restrict__ Qp, const short* __restrict__ Kp,
    const short* __restrict__ Vt, const float* __restrict__ mask,
    const float* __restrict__ ml,
    float* __restrict__ Ob, short* __restrict__ Obb) {
  __shared__ short Kl[64][64];     // 8 KB, XOR-swizzled
  __shared__ short Vl[64][64];     // 8 KB
  __shared__ short Pl[4][16][64];  // 8 KB, per-wave
  const int t = threadIdx.x, lane = t & 63, w = t >> 6;
  const int c = lane & 15, g = lane >> 4;
  // XCD-aware swizzle: each XCD owns 8 (b,h) heads; 16 q-tiles per head contiguous
  const int hw = blockIdx.x;
  const int L = (hw & 7) * 128 + (hw >> 3);
  const int qt = L & 15, hb = L >> 4;
  const int b = hb & 7, h = hb >> 3;
  const int n0 = qt * 64;
  const float scale2 = 0.06375870724f;  // log2(e)/sqrt(512)

  const short* Kg = Kp + (size_t)(b * 1024) * 512 + h * 64;
  const short* Vg = Vt + (size_t)((b * 8 + h) * 64) * 1024;
  const float* Lg = ml + b * 1024;
  const int srow = lane >> 3;
  const int sswz = ((lane & 7) ^ srow) << 3;
  const int r0 = w * 16, r1 = w * 16 + 8;
  const int swc = (c & 7) << 3;

  bf16x8 qf0, qf1;
  {
    const short* qptr = Qp + ((size_t)(b * 1024 + n0 + w * 16 + c) * 512 + h * 64 + 8 * g);
    qf0 = *(const bf16x8*)qptr;
    qf1 = *(const bf16x8*)(qptr + 32);
  }
  bf16x8 ones;
#pragma unroll
  for (int k = 0; k < 8; ++k) ones[k] = (short)0x3F80;  // bf16 1.0

  const f32x4 zz = {0.f, 0.f, 0.f, 0.f};
  f32x4 o[4];
  o[0] = zz; o[1] = zz; o[2] = zz; o[3] = zz;
  f32x4 suma = zz;  // rowsum(q=4g+i) accumulated by MFMA

  // stage tile 0
  GLOAD_LDS16(Kg + (size_t)(r0 + srow) * 512 + sswz, &Kl[r0][0]);
  GLOAD_LDS16(Kg + (size_t)(r1 + srow) * 512 + sswz, &Kl[r1][0]);
  GLOAD_LDS16(Vg + (size_t)(r0 + srow) * 1024 + sswz, &Vl[r0][0]);
  GLOAD_LDS16(Vg + (size_t)(r1 + srow) * 1024 + sswz, &Vl[r1][0]);
  __syncthreads();

#pragma unroll 1
  for (int kvt = 0; kvt < 16; ++kvt) {
    // additive log-mask (tiny, L1/L2 resident)
    float4 lm[4];
#pragma unroll
    for (int j = 0; j < 4; ++j)
      lm[j] = *(const float4*)(Lg + kvt * 64 + 16 * j + 4 * g);

    // QK^T swapped: lane holds S^T[kv=16j+4g+i][q=c]
    f32x4 s[4];
    __builtin_amdgcn_s_setprio(1);
#pragma unroll
    for (int j = 0; j < 4; ++j) {
      f32x4 sj = zz;
      sj = MFMA16(*(const bf16x8*)(&Kl[16 * j + c][(8 * g) ^ swc]), qf0, sj);
      sj = MFMA16(*(const bf16x8*)(&Kl[16 * j + c][(32 + 8 * g) ^ swc]), qf1, sj);
      s[j] = sj;
    }
    __builtin_amdgcn_s_setprio(0);

    // no-max softmax numerator: p = exp2(scale2*s + lm); masked -> 0
#pragma unroll
    for (int j = 0; j < 4; ++j) {
      float p0 = exp2f(fmaf(scale2, s[j][0], lm[j].x));
      float p1 = exp2f(fmaf(scale2, s[j][1], lm[j].y));
      float p2 = exp2f(fmaf(scale2, s[j][2], lm[j].z));
      float p3 = exp2f(fmaf(scale2, s[j][3], lm[j].w));
      uint2 pw; pw.x = cvtpk(p0, p1); pw.y = cvtpk(p2, p3);
      *(uint2*)(&Pl[w][c][(16 * j + 4 * g) ^ swc]) = pw;
    }

    // PV + rowsum-via-MFMA
    __builtin_amdgcn_s_setprio(1);
#pragma unroll
    for (int ks = 0; ks < 2; ++ks) {
      bf16x8 pa = *(const bf16x8*)(&Pl[w][c][(ks * 32 + 8 * g) ^ swc]);
      suma = MFMA16(pa, ones, suma);
#pragma unroll
      for (int nb = 0; nb < 4; ++nb) {
        bf16x8 vb = *(const bf16x8*)(&Vl[16 * nb + c][(ks * 32 + 8 * g) ^ swc]);
        o[nb] = MFMA16(pa, vb, o[nb]);
      }
    }
    __builtin_amdgcn_s_setprio(0);

    if (kvt < 15) {
      __syncthreads();  // all waves done reading Kl/Vl
      const int kr = (kvt + 1) * 64;
      GLOAD_LDS16(Kg + (size_t)(kr + r0 + srow) * 512 + sswz, &Kl[r0][0]);
      GLOAD_LDS16(Kg + (size_t)(kr + r1 + srow) * 512 + sswz, &Kl[r1][0]);
      GLOAD_LDS16(Vg + (size_t)(r0 + srow) * 1024 + kr + sswz, &Vl[r0][0]);
      GLOAD_LDS16(Vg + (size_t)(r1 + srow) * 1024 + kr + sswz, &Vl[r1][0]);
      __syncthreads();  // staged data visible
    }
  }

  float inv[4], mk1[4];
#pragma unroll
  for (int i = 0; i < 4; ++i) {
    inv[i] = __builtin_amdgcn_rcpf(suma[i] + 1e-16f);
    mk1[i] = mask[b * 1024 + n0 + w * 16 + 4 * g + i];
  }
#pragma unroll
  for (int nb = 0; nb < 4; ++nb) {
    int colg = h * 64 + 16 * nb + c;
#pragma unroll
    for (int i = 0; i < 4; ++i) {
      int row = n0 + w * 16 + 4 * g + i;
      float att = o[nb][i] * inv[i];
      float qv = b2f(*(const unsigned short*)(Qp + (size_t)(b * 1024 + row) * 512 + colg));
      float res = qv + mk1[i] * att;
      size_t off = (size_t)(b * 1024 + row) * 512 + colg;
      Ob[off] = res;
      Obb[off] = (short)f2b(res);
    }
  }
}

// ---------------- final: out = Ob + relu((Obb@Wo + bo) * mask)
__global__ __launch_bounds__(256) void final2_kernel(
    const short* __restrict__ Obb, const float* __restrict__ Obf,
    const short* __restrict__ Wto, const float* __restrict__ bo,
    const float* __restrict__ maskf, float* __restrict__ out) {
  __shared__ short Al[128 * 64];
  __shared__ short Bl[128 * 64];
  const int m0 = blockIdx.x * 128, n0 = blockIdx.y * 128;
  const int t = threadIdx.x;
  const f32x4 zz = {0.f, 0.f, 0.f, 0.f};
  f32x4 acc[4][4];
#pragma unroll
  for (int mi = 0; mi < 4; ++mi)
#pragma unroll
    for (int ni = 0; ni < 4; ++ni) acc[mi][ni] = zz;
  gemm_bf16_core(Obb, Wto + n0 * 512, Al, Bl, m0, t, acc);

  const int lane = t & 63, w = t >> 6;
  const int c = lane & 15, g = lane >> 4;
  const int wr = w >> 1, wc = w & 1;
  float mk[4][4];
#pragma unroll
  for (int mi = 0; mi < 4; ++mi) {
    int mbase = m0 + wr * 64 + mi * 16 + 4 * g;
#pragma unroll
    for (int i = 0; i < 4; ++i) mk[mi][i] = maskf[mbase + i];
  }
#pragma unroll
  for (int ni = 0; ni < 4; ++ni) {
    int n = n0 + wc * 64 + ni * 16 + c;
    float bval = bo[n];
#pragma unroll
    for (int mi = 0; mi < 4; ++mi) {
      int mbase = m0 + wr * 64 + mi * 16 + 4 * g;
#pragma unroll
      for (int i = 0; i < 4; ++i) {
        float v = (acc[mi][ni][i] + bval) * mk[mi][i];
        v = fmaxf(v, 0.f);
        size_t off = (size_t)(mbase + i) * 512 + n;
        out[off] = Obf[off] + v;
      }
    }
  }
}

extern "C" void kernel_launch(void* const* d_in, const int* in_sizes, int n_in,
                              void* d_out, int out_size, void* d_ws, size_t ws_size,
                              hipStream_t stream) {
  (void)in_sizes; (void)n_in; (void)ws_size;
  const float* Q    = (const float*)d_in[0];
  const float* K    = (const float*)d_in[1];
  const float* mask = (const float*)d_in[2];
  const float* Wq   = (const float*)d_in[3];
  const float* bq   = (const float*)d_in[4];
  const float* Wk   = (const float*)d_in[5];
  const float* bk   = (const float*)d_in[6];
  const float* Wv   = (const float*)d_in[7];
  const float* bv   = (const float*)d_in[8];
  const float* Wo   = (const float*)d_in[9];
  const float* bo   = (const float*)d_in[10];

  char* ws = (char*)d_ws;
  const size_t MB = 1048576;
  short* Wt4 = (short*)ws;                 // 2 MiB: 4x 512x512 bf16
  short* Qb  = (short*)(ws + 2 * MB);      // 8 MiB
  short* Kb  = (short*)(ws + 10 * MB);     // 8 MiB
  short* Qp  = (short*)(ws + 18 * MB);     // 8 MiB
  short* Kp  = (short*)(ws + 26 * MB);     // 8 MiB
  short* Vt  = (short*)(ws + 34 * MB);     // 8 MiB: [B][H][64][1024]
  short* Obb = (short*)(ws + 42 * MB);     // 8 MiB
  float* Ob  = (float*)(ws + 2 * MB);      // 16 MiB (reuses Qb/Kb after proj)
  float* out = (float*)d_out;
  // additive logmask lives in the tail of d_out (fully overwritten by final2)
  float* ml  = out + (out_size - 8192);

  wtrans_kernel<<<dim3(8, 8, 4), 256, 0, stream>>>(Wq, Wk, Wv, Wo, Wt4);
  cvt_kernel<<<dim3(2048, 2), 256, 0, stream>>>(Q, K, mask, Qb, Kb, ml);
  proj2_kernel<<<dim3(64, 12), 256, 0, stream>>>(Qb, Kb, Wt4, bq, bk, bv, mask, Qp, Kp, Vt);
  attn_kernel<<<dim3(1024), 256, 0, stream>>>(Qp, Kp, Vt, mask, ml, Ob, Obb);
  final2_kernel<<<dim3(64, 4), 256, 0, stream>>>(Obb, Ob, Wt4 + 3 * 262144, bo, mask, out);
}

// Round 6
// 98.825 us; speedup vs baseline: 1.9218x; 1.0242x over previous
//
#include <hip/hip_runtime.h>

typedef short bf16x8 __attribute__((ext_vector_type(8)));
typedef float f32x4 __attribute__((ext_vector_type(4)));

#define MFMA16(a, b, c) __builtin_amdgcn_mfma_f32_16x16x32_bf16((a), (b), (c), 0, 0, 0)

#define GLOAD_LDS16(g, l)                                              \
  __builtin_amdgcn_global_load_lds(                                    \
      (const __attribute__((address_space(1))) unsigned int*)(g),      \
      (__attribute__((address_space(3))) unsigned int*)(l), 16, 0, 0)

__device__ __forceinline__ unsigned short f2b(float f) {
  union { float f; unsigned int u; } x; x.f = f;
  unsigned int r = x.u + 0x7FFFu + ((x.u >> 16) & 1u);
  return (unsigned short)(r >> 16);
}
__device__ __forceinline__ float b2f(unsigned short h) {
  union { unsigned int u; float f; } x; x.u = ((unsigned int)h) << 16;
  return x.f;
}
__device__ __forceinline__ unsigned int cvtpk(float lo, float hi) {
  unsigned int r;
  asm("v_cvt_pk_bf16_f32 %0, %1, %2" : "=v"(r) : "v"(lo), "v"(hi));
  return r;
}

// ---------------- weight transpose+convert: W[512][512] f32 -> Wt[512n][512k] bf16
__global__ __launch_bounds__(256) void wtrans_kernel(
    const float* __restrict__ Wq, const float* __restrict__ Wk,
    const float* __restrict__ Wv, const float* __restrict__ Wo,
    short* __restrict__ Wt) {
  __shared__ float tile[64][65];
  const int z = blockIdx.z;
  const float* W = (z == 0) ? Wq : (z == 1) ? Wk : (z == 2) ? Wv : Wo;
  const int k0 = blockIdx.x * 64, n0 = blockIdx.y * 64;
  const int t = threadIdx.x;
  const int r = t >> 4, cc = (t & 15) * 4;
#pragma unroll
  for (int it = 0; it < 4; ++it) {
    int row = r + it * 16;
    const float4 v = *(const float4*)(W + (k0 + row) * 512 + n0 + cc);
    tile[row][cc + 0] = v.x; tile[row][cc + 1] = v.y;
    tile[row][cc + 2] = v.z; tile[row][cc + 3] = v.w;
  }
  __syncthreads();
  short* out = Wt + z * (512 * 512);
#pragma unroll
  for (int it = 0; it < 4; ++it) {
    int nrow = r + it * 16;
    unsigned int u0 = cvtpk(tile[cc + 0][nrow], tile[cc + 1][nrow]);
    unsigned int u1 = cvtpk(tile[cc + 2][nrow], tile[cc + 3][nrow]);
    uint2 uv; uv.x = u0; uv.y = u1;
    *(uint2*)(out + (n0 + nrow) * 512 + k0 + cc) = uv;
  }
}

// ---------------- convert Q,K f32 -> bf16; also build additive logmask ml
__global__ __launch_bounds__(256) void cvt_kernel(
    const float* __restrict__ Q, const float* __restrict__ K,
    const float* __restrict__ mask,
    short* __restrict__ Qb, short* __restrict__ Kb, float* __restrict__ ml) {
  if (blockIdx.y == 0 && blockIdx.x < 4) {
    int i = (blockIdx.x * 256 + threadIdx.x) * 8;
    float4 a = *(const float4*)(mask + i);
    float4 bb = *(const float4*)(mask + i + 4);
    float4 ra, rb;
    ra.x = (a.x != 0.f) ? 0.f : -1e30f;
    ra.y = (a.y != 0.f) ? 0.f : -1e30f;
    ra.z = (a.z != 0.f) ? 0.f : -1e30f;
    ra.w = (a.w != 0.f) ? 0.f : -1e30f;
    rb.x = (bb.x != 0.f) ? 0.f : -1e30f;
    rb.y = (bb.y != 0.f) ? 0.f : -1e30f;
    rb.z = (bb.z != 0.f) ? 0.f : -1e30f;
    rb.w = (bb.w != 0.f) ? 0.f : -1e30f;
    *(float4*)(ml + i) = ra;
    *(float4*)(ml + i + 4) = rb;
  }
  const float* src = blockIdx.y ? K : Q;
  short* dst = blockIdx.y ? Kb : Qb;
  int i = (blockIdx.x * 256 + threadIdx.x) * 8;
  float4 v0 = *(const float4*)(src + i);
  float4 v1 = *(const float4*)(src + i + 4);
  uint2 a, b;
  a.x = cvtpk(v0.x, v0.y); a.y = cvtpk(v0.z, v0.w);
  b.x = cvtpk(v1.x, v1.y); b.y = cvtpk(v1.z, v1.w);
  *(uint2*)(dst + i) = a;
  *(uint2*)(dst + i + 4) = b;
}

// ---------------- GEMM mainloop: 128x128 tile, BK=64, dbuf LDS + counted vmcnt + T2 swizzle
// Al/Bl are [2][128][64] shorts (16 KB each buffer half).
__device__ __forceinline__ void gemm_bf16_core(
    const short* __restrict__ A, const short* __restrict__ Wt,
    short* Al, short* Bl, int m0, int t, f32x4 acc[4][4]) {
  const int lane = t & 63, w = t >> 6;
  const int c = lane & 15, g = lane >> 4;
  const int wr = w >> 1, wc = w & 1;
  const int lr = lane >> 3;
  const int sswz = ((lane & 7) ^ lr) << 3;  // pre-swizzled source slot (shorts)
  const int swc = (c & 7) << 3;             // read-side XOR key (shorts)

  auto STAGE = [&](int kt, int buf) {
    short* Ad = Al + buf * 8192;
    short* Bd = Bl + buf * 8192;
#pragma unroll
    for (int it = 0; it < 4; ++it) {
      int row = w * 32 + it * 8;
      GLOAD_LDS16(A + (size_t)(m0 + row + lr) * 512 + kt * 64 + sswz, Ad + row * 64);
      GLOAD_LDS16(Wt + (size_t)(row + lr) * 512 + kt * 64 + sswz, Bd + row * 64);
    }
  };

  STAGE(0, 0);
  STAGE(1, 1);

  for (int kt = 0; kt < 8; ++kt) {
    if (kt < 7) { asm volatile("s_waitcnt vmcnt(8)" ::: "memory"); }
    else        { asm volatile("s_waitcnt vmcnt(0)" ::: "memory"); }
    __builtin_amdgcn_s_barrier();
    __builtin_amdgcn_sched_barrier(0);
    const short* Ac = Al + (kt & 1) * 8192;
    const short* Bc = Bl + (kt & 1) * 8192;
    __builtin_amdgcn_s_setprio(1);
#pragma unroll
    for (int kc = 0; kc < 2; ++kc) {
      bf16x8 af[4], bfr[4];
#pragma unroll
      for (int mi = 0; mi < 4; ++mi) {
        int r = wr * 64 + mi * 16 + c;
        af[mi] = *(const bf16x8*)(Ac + r * 64 + ((kc * 32 + 8 * g) ^ swc));
      }
#pragma unroll
      for (int ni = 0; ni < 4; ++ni) {
        int r = wc * 64 + ni * 16 + c;
        bfr[ni] = *(const bf16x8*)(Bc + r * 64 + ((kc * 32 + 8 * g) ^ swc));
      }
#pragma unroll
      for (int mi = 0; mi < 4; ++mi)
#pragma unroll
        for (int ni = 0; ni < 4; ++ni)
          acc[mi][ni] = MFMA16(af[mi], bfr[ni], acc[mi][ni]);
    }
    __builtin_amdgcn_s_setprio(0);
    __builtin_amdgcn_sched_barrier(0);
    __builtin_amdgcn_s_barrier();
    __builtin_amdgcn_sched_barrier(0);
    if (kt < 6) STAGE(kt + 2, kt & 1);
  }
}

// ---------------- fused projections
__global__ __launch_bounds__(256) void proj2_kernel(
    const short* __restrict__ Qb, const short* __restrict__ Kb,
    const short* __restrict__ Wt4,
    const float* __restrict__ bq, const float* __restrict__ bk, const float* __restrict__ bv,
    const float* __restrict__ maskf,
    short* __restrict__ Qp, short* __restrict__ Kp, short* __restrict__ Vt) {
  __shared__ short Al[2 * 128 * 64];
  __shared__ short Bl[2 * 128 * 64];
  const int by = blockIdx.y;
  const int m0 = blockIdx.x * 128;
  const int t = threadIdx.x;
  const short* A;
  const short* Wt;
  const float* bias;
  int nbase;
  if (by < 4) { A = Qb; nbase = by * 128; Wt = Wt4 + nbase * 512; bias = bq; }
  else if (by < 8) { A = Kb; nbase = (by - 4) * 128; Wt = Wt4 + 262144 + nbase * 512; bias = bk; }
  else { A = Kb; nbase = (by - 8) * 128; Wt = Wt4 + 524288 + nbase * 512; bias = bv; }

  const f32x4 zz = {0.f, 0.f, 0.f, 0.f};
  f32x4 acc[4][4];
#pragma unroll
  for (int mi = 0; mi < 4; ++mi)
#pragma unroll
    for (int ni = 0; ni < 4; ++ni) acc[mi][ni] = zz;
  gemm_bf16_core(A, Wt, Al, Bl, m0, t, acc);

  const int lane = t & 63, w = t >> 6;
  const int c = lane & 15, g = lane >> 4;
  const int wr = w >> 1, wc = w & 1;
  float mk[4][4];
#pragma unroll
  for (int mi = 0; mi < 4; ++mi) {
    int mbase = m0 + wr * 64 + mi * 16 + 4 * g;
#pragma unroll
    for (int i = 0; i < 4; ++i) mk[mi][i] = maskf[mbase + i];
  }
  if (by < 8) {
    short* out = (by < 4) ? Qp : Kp;
#pragma unroll
    for (int ni = 0; ni < 4; ++ni) {
      int n = nbase + wc * 64 + ni * 16 + c;
      float bval = bias[n];
#pragma unroll
      for (int mi = 0; mi < 4; ++mi) {
        int mbase = m0 + wr * 64 + mi * 16 + 4 * g;
#pragma unroll
        for (int i = 0; i < 4; ++i)
          out[(size_t)(mbase + i) * 512 + n] = (short)f2b((acc[mi][ni][i] + bval) * mk[mi][i]);
      }
    }
  } else {
#pragma unroll
    for (int ni = 0; ni < 4; ++ni) {
      int d = nbase + wc * 64 + ni * 16 + c;
      int h = d >> 6, dd = d & 63;
      float bval = bias[d];
#pragma unroll
      for (int mi = 0; mi < 4; ++mi) {
        int mbase = m0 + wr * 64 + mi * 16 + 4 * g;
        int bi = mbase >> 10, seq0 = mbase & 1023;
        unsigned int u0 = cvtpk((acc[mi][ni][0] + bval) * mk[mi][0],
                                (acc[mi][ni][1] + bval) * mk[mi][1]);
        unsigned int u1 = cvtpk((acc[mi][ni][2] + bval) * mk[mi][2],
                                (acc[mi][ni][3] + bval) * mk[mi][3]);
        uint2 uv; uv.x = u0; uv.y = u1;
        *(uint2*)(Vt + ((size_t)(bi * 8 + h) * 64 + dd) * 1024 + seq0) = uv;
      }
    }
  }
}

// ---------------- flash attention per (h,b): dbuf KV + counted vmcnt, no-max softmax
__global__ __launch_bounds__(256) void attn_kernel(
    const short* __restrict__ Qp, const short* __restrict__ Kp,
    const short* __restrict__ Vt, const float* __restrict__ mask,
    const float* __restrict__ ml,
    float* __restrict__ Ob, short* __restrict__ Obb) {
  __shared__ short Kl[2][64][64];   // 16 KB
  __shared__ short Vl[2][64][64];   // 16 KB
  __shared__ short Pl[4][16][64];   //  8 KB per-wave
  __shared__ float Mlds[1024];      //  4 KB additive logmask row
  const int t = threadIdx.x, lane = t & 63, w = t >> 6;
  const int c = lane & 15, g = lane >> 4;
  const int hw = blockIdx.x;
  const int L = (hw & 7) * 128 + (hw >> 3);
  const int qt = L & 15, hb = L >> 4;
  const int b = hb & 7, h = hb >> 3;
  const int n0 = qt * 64;
  const float scale2 = 0.06375870724f;  // log2(e)/sqrt(512)

  const short* Kg = Kp + (size_t)(b * 1024) * 512 + h * 64;
  const short* Vg = Vt + (size_t)((b * 8 + h) * 64) * 1024;
  const float* Lg = ml + b * 1024;
  const int srow = lane >> 3;
  const int sswz = ((lane & 7) ^ srow) << 3;
  const int r0 = w * 16, r1 = w * 16 + 8;
  const int swc = (c & 7) << 3;

  bf16x8 qf0, qf1;
  {
    const short* qptr = Qp + ((size_t)(b * 1024 + n0 + w * 16 + c) * 512 + h * 64 + 8 * g);
    qf0 = *(const bf16x8*)qptr;
    qf1 = *(const bf16x8*)(qptr + 32);
  }
  bf16x8 ones;
#pragma unroll
  for (int k = 0; k < 8; ++k) ones[k] = (short)0x3F80;  // bf16 1.0

  auto STAGEKV = [&](int kvt, int buf) {
    const int kr = kvt * 64;
    GLOAD_LDS16(Kg + (size_t)(kr + r0 + srow) * 512 + sswz, &Kl[buf][r0][0]);
    GLOAD_LDS16(Kg + (size_t)(kr + r1 + srow) * 512 + sswz, &Kl[buf][r1][0]);
    GLOAD_LDS16(Vg + (size_t)(r0 + srow) * 1024 + kr + sswz, &Vl[buf][r0][0]);
    GLOAD_LDS16(Vg + (size_t)(r1 + srow) * 1024 + kr + sswz, &Vl[buf][r1][0]);
  };

  // prologue: logmask row (1 load/wave) + tiles 0,1
  GLOAD_LDS16(Lg + w * 256 + lane * 4, &Mlds[w * 256]);
  STAGEKV(0, 0);
  STAGEKV(1, 1);

  const f32x4 zz = {0.f, 0.f, 0.f, 0.f};
  f32x4 o[4];
  o[0] = zz; o[1] = zz; o[2] = zz; o[3] = zz;
  f32x4 suma = zz;

#pragma unroll 1
  for (int kvt = 0; kvt < 16; ++kvt) {
    if (kvt < 15) { asm volatile("s_waitcnt vmcnt(4)" ::: "memory"); }
    else          { asm volatile("s_waitcnt vmcnt(0)" ::: "memory"); }
    __builtin_amdgcn_s_barrier();
    __builtin_amdgcn_sched_barrier(0);
    const int cur = kvt & 1;

    // additive log-mask from LDS (no VMEM in loop body)
    float4 lm[4];
#pragma unroll
    for (int j = 0; j < 4; ++j)
      lm[j] = *(const float4*)(&Mlds[kvt * 64 + 16 * j + 4 * g]);

    // QK^T swapped: lane holds S^T[kv=16j+4g+i][q=c]
    f32x4 s[4];
    __builtin_amdgcn_s_setprio(1);
#pragma unroll
    for (int j = 0; j < 4; ++j) {
      f32x4 sj = zz;
      sj = MFMA16(*(const bf16x8*)(&Kl[cur][16 * j + c][(8 * g) ^ swc]), qf0, sj);
      sj = MFMA16(*(const bf16x8*)(&Kl[cur][16 * j + c][(32 + 8 * g) ^ swc]), qf1, sj);
      s[j] = sj;
    }
    __builtin_amdgcn_s_setprio(0);

    // no-max softmax numerator: p = exp2(scale2*s + lm); masked -> 0
#pragma unroll
    for (int j = 0; j < 4; ++j) {
      float p0 = exp2f(fmaf(scale2, s[j][0], lm[j].x));
      float p1 = exp2f(fmaf(scale2, s[j][1], lm[j].y));
      float p2 = exp2f(fmaf(scale2, s[j][2], lm[j].z));
      float p3 = exp2f(fmaf(scale2, s[j][3], lm[j].w));
      uint2 pw; pw.x = cvtpk(p0, p1); pw.y = cvtpk(p2, p3);
      *(uint2*)(&Pl[w][c][(16 * j + 4 * g) ^ swc]) = pw;
    }

    // PV + rowsum-via-MFMA
    __builtin_amdgcn_s_setprio(1);
#pragma unroll
    for (int ks = 0; ks < 2; ++ks) {
      bf16x8 pa = *(const bf16x8*)(&Pl[w][c][(ks * 32 + 8 * g) ^ swc]);
      suma = MFMA16(pa, ones, suma);
#pragma unroll
      for (int nb = 0; nb < 4; ++nb) {
        bf16x8 vb = *(const bf16x8*)(&Vl[cur][16 * nb + c][(ks * 32 + 8 * g) ^ swc]);
        o[nb] = MFMA16(pa, vb, o[nb]);
      }
    }
    __builtin_amdgcn_s_setprio(0);

    __builtin_amdgcn_sched_barrier(0);
    __builtin_amdgcn_s_barrier();   // all waves done reading buf[cur]
    __builtin_amdgcn_sched_barrier(0);
    if (kvt < 14) STAGEKV(kvt + 2, cur);
  }

  float inv[4], mk1[4];
#pragma unroll
  for (int i = 0; i < 4; ++i) {
    inv[i] = __builtin_amdgcn_rcpf(suma[i] + 1e-16f);
    mk1[i] = mask[b * 1024 + n0 + w * 16 + 4 * g + i];
  }
#pragma unroll
  for (int nb = 0; nb < 4; ++nb) {
    int colg = h * 64 + 16 * nb + c;
#pragma unroll
    for (int i = 0; i < 4; ++i) {
      int row = n0 + w * 16 + 4 * g + i;
      float att = o[nb][i] * inv[i];
      float qv = b2f(*(const unsigned short*)(Qp + (size_t)(b * 1024 + row) * 512 + colg));
      float res = qv + mk1[i] * att;
      size_t off = (size_t)(b * 1024 + row) * 512 + colg;
      Ob[off] = res;
      Obb[off] = (short)f2b(res);
    }
  }
}

// ---------------- final: out = Ob + relu((Obb@Wo + bo) * mask)
__global__ __launch_bounds__(256) void final2_kernel(
    const short* __restrict__ Obb, const float* __restrict__ Obf,
    const short* __restrict__ Wto, const float* __restrict__ bo,
    const float* __restrict__ maskf, float* __restrict__ out) {
  __shared__ short Al[2 * 128 * 64];
  __shared__ short Bl[2 * 128 * 64];
  const int m0 = blockIdx.x * 128, n0 = blockIdx.y * 128;
  const int t = threadIdx.x;
  const f32x4 zz = {0.f, 0.f, 0.f, 0.f};
  f32x4 acc[4][4];
#pragma unroll
  for (int mi = 0; mi < 4; ++mi)
#pragma unroll
    for (int ni = 0; ni < 4; ++ni) acc[mi][ni] = zz;
  gemm_bf16_core(Obb, Wto + n0 * 512, Al, Bl, m0, t, acc);

  const int lane = t & 63, w = t >> 6;
  const int c = lane & 15, g = lane >> 4;
  const int wr = w >> 1, wc = w & 1;
  float mk[4][4];
#pragma unroll
  for (int mi = 0; mi < 4; ++mi) {
    int mbase = m0 + wr * 64 + mi * 16 + 4 * g;
#pragma unroll
    for (int i = 0; i < 4; ++i) mk[mi][i] = maskf[mbase + i];
  }
#pragma unroll
  for (int ni = 0; ni < 4; ++ni) {
    int n = n0 + wc * 64 + ni * 16 + c;
    float bval = bo[n];
#pragma unroll
    for (int mi = 0; mi < 4; ++mi) {
      int mbase = m0 + wr * 64 + mi * 16 + 4 * g;
#pragma unroll
      for (int i = 0; i < 4; ++i) {
        float v = (acc[mi][ni][i] + bval) * mk[mi][i];
        v = fmaxf(v, 0.f);
        size_t off = (size_t)(mbase + i) * 512 + n;
        out[off] = Obf[off] + v;
      }
    }
  }
}

extern "C" void kernel_launch(void* const* d_in, const int* in_sizes, int n_in,
                              void* d_out, int out_size, void* d_ws, size_t ws_size,
                              hipStream_t stream) {
  (void)in_sizes; (void)n_in; (void)ws_size;
  const float* Q    = (const float*)d_in[0];
  const float* K    = (const float*)d_in[1];
  const float* mask = (const float*)d_in[2];
  const float* Wq   = (const float*)d_in[3];
  const float* bq   = (const float*)d_in[4];
  const float* Wk   = (const float*)d_in[5];
  const float* bk   = (const float*)d_in[6];
  const float* Wv   = (const float*)d_in[7];
  const float* bv   = (const float*)d_in[8];
  const float* Wo   = (const float*)d_in[9];
  const float* bo   = (const float*)d_in[10];

  char* ws = (char*)d_ws;
  const size_t MB = 1048576;
  short* Wt4 = (short*)ws;                 // 2 MiB: 4x 512x512 bf16
  short* Qb  = (short*)(ws + 2 * MB);      // 8 MiB
  short* Kb  = (short*)(ws + 10 * MB);     // 8 MiB
  short* Qp  = (short*)(ws + 18 * MB);     // 8 MiB
  short* Kp  = (short*)(ws + 26 * MB);     // 8 MiB
  short* Vt  = (short*)(ws + 34 * MB);     // 8 MiB: [B][H][64][1024]
  short* Obb = (short*)(ws + 42 * MB);     // 8 MiB
  float* Ob  = (float*)(ws + 2 * MB);      // 16 MiB (reuses Qb/Kb after proj)
  float* out = (float*)d_out;
  // additive logmask lives in the tail of d_out (fully overwritten by final2)
  float* ml  = out + (out_size - 8192);

  wtrans_kernel<<<dim3(8, 8, 4), 256, 0, stream>>>(Wq, Wk, Wv, Wo, Wt4);
  cvt_kernel<<<dim3(2048, 2), 256, 0, stream>>>(Q, K, mask, Qb, Kb, ml);
  proj2_kernel<<<dim3(64, 12), 256, 0, stream>>>(Qb, Kb, Wt4, bq, bk, bv, mask, Qp, Kp, Vt);
  attn_kernel<<<dim3(1024), 256, 0, stream>>>(Qp, Kp, Vt, mask, ml, Ob, Obb);
  final2_kernel<<<dim3(64, 4), 256, 0, stream>>>(Obb, Ob, Wt4 + 3 * 262144, bo, mask, out);
}

// Round 7
// 95.938 us; speedup vs baseline: 1.9796x; 1.0301x over previous
//
#include <hip/hip_runtime.h>

typedef short bf16x8 __attribute__((ext_vector_type(8)));
typedef float f32x4 __attribute__((ext_vector_type(4)));

#define MFMA16(a, b, c) __builtin_amdgcn_mfma_f32_16x16x32_bf16((a), (b), (c), 0, 0, 0)

#define GLOAD_LDS16(g, l)                                              \
  __builtin_amdgcn_global_load_lds(                                    \
      (const __attribute__((address_space(1))) unsigned int*)(g),      \
      (__attribute__((address_space(3))) unsigned int*)(l), 16, 0, 0)

__device__ __forceinline__ unsigned short f2b(float f) {
  union { float f; unsigned int u; } x; x.f = f;
  unsigned int r = x.u + 0x7FFFu + ((x.u >> 16) & 1u);
  return (unsigned short)(r >> 16);
}
__device__ __forceinline__ float b2f(unsigned short h) {
  union { unsigned int u; float f; } x; x.u = ((unsigned int)h) << 16;
  return x.f;
}
__device__ __forceinline__ unsigned int cvtpk(float lo, float hi) {
  unsigned int r;
  asm("v_cvt_pk_bf16_f32 %0, %1, %2" : "=v"(r) : "v"(lo), "v"(hi));
  return r;
}

// ---------------- weight transpose+convert: W[512][512] f32 -> Wt[512n][512k] bf16
__global__ __launch_bounds__(256) void wtrans_kernel(
    const float* __restrict__ Wq, const float* __restrict__ Wk,
    const float* __restrict__ Wv, const float* __restrict__ Wo,
    short* __restrict__ Wt) {
  __shared__ float tile[64][65];
  const int z = blockIdx.z;
  const float* W = (z == 0) ? Wq : (z == 1) ? Wk : (z == 2) ? Wv : Wo;
  const int k0 = blockIdx.x * 64, n0 = blockIdx.y * 64;
  const int t = threadIdx.x;
  const int r = t >> 4, cc = (t & 15) * 4;
#pragma unroll
  for (int it = 0; it < 4; ++it) {
    int row = r + it * 16;
    const float4 v = *(const float4*)(W + (k0 + row) * 512 + n0 + cc);
    tile[row][cc + 0] = v.x; tile[row][cc + 1] = v.y;
    tile[row][cc + 2] = v.z; tile[row][cc + 3] = v.w;
  }
  __syncthreads();
  short* out = Wt + z * (512 * 512);
#pragma unroll
  for (int it = 0; it < 4; ++it) {
    int nrow = r + it * 16;
    unsigned int u0 = cvtpk(tile[cc + 0][nrow], tile[cc + 1][nrow]);
    unsigned int u1 = cvtpk(tile[cc + 2][nrow], tile[cc + 3][nrow]);
    uint2 uv; uv.x = u0; uv.y = u1;
    *(uint2*)(out + (n0 + nrow) * 512 + k0 + cc) = uv;
  }
}

// ---------------- convert Q,K f32 -> bf16; also build additive logmask ml
__global__ __launch_bounds__(256) void cvt_kernel(
    const float* __restrict__ Q, const float* __restrict__ K,
    const float* __restrict__ mask,
    short* __restrict__ Qb, short* __restrict__ Kb, float* __restrict__ ml) {
  if (blockIdx.y == 0 && blockIdx.x < 4) {
    int i = (blockIdx.x * 256 + threadIdx.x) * 8;
    float4 a = *(const float4*)(mask + i);
    float4 bb = *(const float4*)(mask + i + 4);
    float4 ra, rb;
    ra.x = (a.x != 0.f) ? 0.f : -1e30f;
    ra.y = (a.y != 0.f) ? 0.f : -1e30f;
    ra.z = (a.z != 0.f) ? 0.f : -1e30f;
    ra.w = (a.w != 0.f) ? 0.f : -1e30f;
    rb.x = (bb.x != 0.f) ? 0.f : -1e30f;
    rb.y = (bb.y != 0.f) ? 0.f : -1e30f;
    rb.z = (bb.z != 0.f) ? 0.f : -1e30f;
    rb.w = (bb.w != 0.f) ? 0.f : -1e30f;
    *(float4*)(ml + i) = ra;
    *(float4*)(ml + i + 4) = rb;
  }
  const float* src = blockIdx.y ? K : Q;
  short* dst = blockIdx.y ? Kb : Qb;
  int i = (blockIdx.x * 256 + threadIdx.x) * 8;
  float4 v0 = *(const float4*)(src + i);
  float4 v1 = *(const float4*)(src + i + 4);
  uint2 a, b;
  a.x = cvtpk(v0.x, v0.y); a.y = cvtpk(v0.z, v0.w);
  b.x = cvtpk(v1.x, v1.y); b.y = cvtpk(v1.z, v1.w);
  *(uint2*)(dst + i) = a;
  *(uint2*)(dst + i + 4) = b;
}

// ---------------- GEMM mainloop: 128x128 tile, BK=64, dbuf LDS + counted vmcnt + T2 swizzle
__device__ __forceinline__ void gemm_bf16_core(
    const short* __restrict__ A, const short* __restrict__ Wt,
    short* Al, short* Bl, int m0, int t, f32x4 acc[4][4]) {
  const int lane = t & 63, w = t >> 6;
  const int c = lane & 15, g = lane >> 4;
  const int wr = w >> 1, wc = w & 1;
  const int lr = lane >> 3;
  const int sswz = ((lane & 7) ^ lr) << 3;  // pre-swizzled source slot (shorts)
  const int swc = (c & 7) << 3;             // read-side XOR key (shorts)

  auto STAGE = [&](int kt, int buf) {
    short* Ad = Al + buf * 8192;
    short* Bd = Bl + buf * 8192;
#pragma unroll
    for (int it = 0; it < 4; ++it) {
      int row = w * 32 + it * 8;
      GLOAD_LDS16(A + (size_t)(m0 + row + lr) * 512 + kt * 64 + sswz, Ad + row * 64);
      GLOAD_LDS16(Wt + (size_t)(row + lr) * 512 + kt * 64 + sswz, Bd + row * 64);
    }
  };

  STAGE(0, 0);
  STAGE(1, 1);

  for (int kt = 0; kt < 8; ++kt) {
    if (kt < 7) { asm volatile("s_waitcnt vmcnt(8)" ::: "memory"); }
    else        { asm volatile("s_waitcnt vmcnt(0)" ::: "memory"); }
    __builtin_amdgcn_s_barrier();
    __builtin_amdgcn_sched_barrier(0);
    const short* Ac = Al + (kt & 1) * 8192;
    const short* Bc = Bl + (kt & 1) * 8192;
    __builtin_amdgcn_s_setprio(1);
#pragma unroll
    for (int kc = 0; kc < 2; ++kc) {
      bf16x8 af[4], bfr[4];
#pragma unroll
      for (int mi = 0; mi < 4; ++mi) {
        int r = wr * 64 + mi * 16 + c;
        af[mi] = *(const bf16x8*)(Ac + r * 64 + ((kc * 32 + 8 * g) ^ swc));
      }
#pragma unroll
      for (int ni = 0; ni < 4; ++ni) {
        int r = wc * 64 + ni * 16 + c;
        bfr[ni] = *(const bf16x8*)(Bc + r * 64 + ((kc * 32 + 8 * g) ^ swc));
      }
#pragma unroll
      for (int mi = 0; mi < 4; ++mi)
#pragma unroll
        for (int ni = 0; ni < 4; ++ni)
          acc[mi][ni] = MFMA16(af[mi], bfr[ni], acc[mi][ni]);
    }
    __builtin_amdgcn_s_setprio(0);
    __builtin_amdgcn_sched_barrier(0);
    __builtin_amdgcn_s_barrier();
    __builtin_amdgcn_sched_barrier(0);
    if (kt < 6) STAGE(kt + 2, kt & 1);
  }
}

// ---------------- fused projections
__global__ __launch_bounds__(256) void proj2_kernel(
    const short* __restrict__ Qb, const short* __restrict__ Kb,
    const short* __restrict__ Wt4,
    const float* __restrict__ bq, const float* __restrict__ bk, const float* __restrict__ bv,
    const float* __restrict__ maskf,
    short* __restrict__ Qp, short* __restrict__ Kp, short* __restrict__ Vt) {
  __shared__ short Al[2 * 128 * 64];
  __shared__ short Bl[2 * 128 * 64];
  const int by = blockIdx.y;
  const int m0 = blockIdx.x * 128;
  const int t = threadIdx.x;
  const short* A;
  const short* Wt;
  const float* bias;
  int nbase;
  if (by < 4) { A = Qb; nbase = by * 128; Wt = Wt4 + nbase * 512; bias = bq; }
  else if (by < 8) { A = Kb; nbase = (by - 4) * 128; Wt = Wt4 + 262144 + nbase * 512; bias = bk; }
  else { A = Kb; nbase = (by - 8) * 128; Wt = Wt4 + 524288 + nbase * 512; bias = bv; }

  const f32x4 zz = {0.f, 0.f, 0.f, 0.f};
  f32x4 acc[4][4];
#pragma unroll
  for (int mi = 0; mi < 4; ++mi)
#pragma unroll
    for (int ni = 0; ni < 4; ++ni) acc[mi][ni] = zz;
  gemm_bf16_core(A, Wt, Al, Bl, m0, t, acc);

  const int lane = t & 63, w = t >> 6;
  const int c = lane & 15, g = lane >> 4;
  const int wr = w >> 1, wc = w & 1;
  float mk[4][4];
#pragma unroll
  for (int mi = 0; mi < 4; ++mi) {
    int mbase = m0 + wr * 64 + mi * 16 + 4 * g;
#pragma unroll
    for (int i = 0; i < 4; ++i) mk[mi][i] = maskf[mbase + i];
  }
  if (by < 8) {
    short* out = (by < 4) ? Qp : Kp;
#pragma unroll
    for (int ni = 0; ni < 4; ++ni) {
      int n = nbase + wc * 64 + ni * 16 + c;
      float bval = bias[n];
#pragma unroll
      for (int mi = 0; mi < 4; ++mi) {
        int mbase = m0 + wr * 64 + mi * 16 + 4 * g;
#pragma unroll
        for (int i = 0; i < 4; ++i)
          out[(size_t)(mbase + i) * 512 + n] = (short)f2b((acc[mi][ni][i] + bval) * mk[mi][i]);
      }
    }
  } else {
#pragma unroll
    for (int ni = 0; ni < 4; ++ni) {
      int d = nbase + wc * 64 + ni * 16 + c;
      int h = d >> 6, dd = d & 63;
      float bval = bias[d];
#pragma unroll
      for (int mi = 0; mi < 4; ++mi) {
        int mbase = m0 + wr * 64 + mi * 16 + 4 * g;
        int bi = mbase >> 10, seq0 = mbase & 1023;
        unsigned int u0 = cvtpk((acc[mi][ni][0] + bval) * mk[mi][0],
                                (acc[mi][ni][1] + bval) * mk[mi][1]);
        unsigned int u1 = cvtpk((acc[mi][ni][2] + bval) * mk[mi][2],
                                (acc[mi][ni][3] + bval) * mk[mi][3]);
        uint2 uv; uv.x = u0; uv.y = u1;
        *(uint2*)(Vt + ((size_t)(bi * 8 + h) * 64 + dd) * 1024 + seq0) = uv;
      }
    }
  }
}

// ---------------- flash attention, KV-split 2-way: grid 2048, 8 tiles/block
// Writes bf16 partial numerator Oacc[s] and f32 partial denominator sacc[s].
__global__ __launch_bounds__(256) void attn_split_kernel(
    const short* __restrict__ Qp, const short* __restrict__ Kp,
    const short* __restrict__ Vt, const float* __restrict__ ml,
    short* __restrict__ OaccA, short* __restrict__ OaccB,
    float* __restrict__ saccA, float* __restrict__ saccB) {
  __shared__ short Kl[64][64];     // 8 KB, XOR-swizzled
  __shared__ short Vl[64][64];     // 8 KB
  __shared__ short Pl[4][16][64];  // 8 KB per-wave
  __shared__ float Mlds[512];      // 2 KB logmask slice
  const int t = threadIdx.x, lane = t & 63, w = t >> 6;
  const int c = lane & 15, g = lane >> 4;
  // XCD swizzle: 256 consecutive logical blocks (8 heads x 32) per XCD
  const int hw = blockIdx.x;
  const int L = (hw & 7) * 256 + (hw >> 3);
  const int head = L >> 5;             // [0,64)
  const int u = L & 31;
  const int qt = u >> 1, s = u & 1;    // q-tile, kv-split half
  const int b = head & 7, h = head >> 3;
  const int n0 = qt * 64;
  const float scale2 = 0.06375870724f;  // log2(e)/sqrt(512)

  const short* Kg = Kp + ((size_t)(b * 1024 + s * 512)) * 512 + h * 64;
  const short* Vg = Vt + (size_t)((b * 8 + h) * 64) * 1024 + s * 512;
  const float* Lg = ml + b * 1024 + s * 512;
  short* OaccS = s ? OaccB : OaccA;
  float* saccS = s ? saccB : saccA;

  const int srow = lane >> 3;
  const int sswz = ((lane & 7) ^ srow) << 3;
  const int r0 = w * 16, r1 = w * 16 + 8;
  const int swc = (c & 7) << 3;

  bf16x8 qf0, qf1;
  {
    const short* qptr = Qp + ((size_t)(b * 1024 + n0 + w * 16 + c) * 512 + h * 64 + 8 * g);
    qf0 = *(const bf16x8*)qptr;
    qf1 = *(const bf16x8*)(qptr + 32);
  }
  bf16x8 ones;
#pragma unroll
  for (int k = 0; k < 8; ++k) ones[k] = (short)0x3F80;  // bf16 1.0

  auto STAGEKV = [&](int kvt) {
    const int kr = kvt * 64;
    GLOAD_LDS16(Kg + (size_t)(kr + r0 + srow) * 512 + sswz, &Kl[r0][0]);
    GLOAD_LDS16(Kg + (size_t)(kr + r1 + srow) * 512 + sswz, &Kl[r1][0]);
    GLOAD_LDS16(Vg + (size_t)(r0 + srow) * 1024 + kr + sswz, &Vl[r0][0]);
    GLOAD_LDS16(Vg + (size_t)(r1 + srow) * 1024 + kr + sswz, &Vl[r1][0]);
  };

  // prologue: logmask slice (waves 0,1) + tile 0
  if (w < 2) GLOAD_LDS16(Lg + w * 256 + lane * 4, &Mlds[w * 256]);
  STAGEKV(0);
  __syncthreads();

  const f32x4 zz = {0.f, 0.f, 0.f, 0.f};
  f32x4 o[4];
  o[0] = zz; o[1] = zz; o[2] = zz; o[3] = zz;
  f32x4 suma = zz;

#pragma unroll 1
  for (int kvt = 0; kvt < 8; ++kvt) {
    // additive log-mask from LDS
    float4 lm[4];
#pragma unroll
    for (int j = 0; j < 4; ++j)
      lm[j] = *(const float4*)(&Mlds[kvt * 64 + 16 * j + 4 * g]);

    // QK^T swapped: lane holds S^T[kv=16j+4g+i][q=c]
    f32x4 sv[4];
    __builtin_amdgcn_s_setprio(1);
#pragma unroll
    for (int j = 0; j < 4; ++j) {
      f32x4 sj = zz;
      sj = MFMA16(*(const bf16x8*)(&Kl[16 * j + c][(8 * g) ^ swc]), qf0, sj);
      sj = MFMA16(*(const bf16x8*)(&Kl[16 * j + c][(32 + 8 * g) ^ swc]), qf1, sj);
      sv[j] = sj;
    }
    __builtin_amdgcn_s_setprio(0);

    // no-max softmax numerator: p = exp2(scale2*s + lm); masked -> 0
#pragma unroll
    for (int j = 0; j < 4; ++j) {
      float p0 = exp2f(fmaf(scale2, sv[j][0], lm[j].x));
      float p1 = exp2f(fmaf(scale2, sv[j][1], lm[j].y));
      float p2 = exp2f(fmaf(scale2, sv[j][2], lm[j].z));
      float p3 = exp2f(fmaf(scale2, sv[j][3], lm[j].w));
      uint2 pw; pw.x = cvtpk(p0, p1); pw.y = cvtpk(p2, p3);
      *(uint2*)(&Pl[w][c][(16 * j + 4 * g) ^ swc]) = pw;
    }

    // PV + rowsum-via-MFMA
    __builtin_amdgcn_s_setprio(1);
#pragma unroll
    for (int ks = 0; ks < 2; ++ks) {
      bf16x8 pa = *(const bf16x8*)(&Pl[w][c][(ks * 32 + 8 * g) ^ swc]);
      suma = MFMA16(pa, ones, suma);
#pragma unroll
      for (int nb = 0; nb < 4; ++nb) {
        bf16x8 vb = *(const bf16x8*)(&Vl[16 * nb + c][(ks * 32 + 8 * g) ^ swc]);
        o[nb] = MFMA16(pa, vb, o[nb]);
      }
    }
    __builtin_amdgcn_s_setprio(0);

    if (kvt < 7) {
      __syncthreads();
      STAGEKV(kvt + 1);
      __syncthreads();
    }
  }

  // epilogue: write bf16 partial numerator + f32 partial denominator
#pragma unroll
  for (int nb = 0; nb < 4; ++nb) {
    int colg = h * 64 + 16 * nb + c;
#pragma unroll
    for (int i = 0; i < 4; ++i) {
      int row = n0 + w * 16 + 4 * g + i;
      OaccS[(size_t)(b * 1024 + row) * 512 + colg] = (short)f2b(o[nb][i]);
    }
  }
  if (c == 0) {
#pragma unroll
    for (int i = 0; i < 4; ++i) {
      int row = n0 + w * 16 + 4 * g + i;
      saccS[(size_t)(b * 1024 + row) * 8 + h] = suma[i];
    }
  }
}

// ---------------- combine: Obb = bf16( Qp + mask * (oA+oB)/(sA+sB) )
__global__ __launch_bounds__(256) void combine_kernel(
    const short* __restrict__ OaccA, const short* __restrict__ OaccB,
    const float* __restrict__ saccA, const float* __restrict__ saccB,
    const short* __restrict__ Qp, const float* __restrict__ mask,
    short* __restrict__ Obb) {
  const int e = (blockIdx.x * 256 + threadIdx.x) * 8;
  const int row = e >> 9;
  const int h = (e & 511) >> 6;
  const float sA = saccA[row * 8 + h], sB = saccB[row * 8 + h];
  const float inv = __builtin_amdgcn_rcpf(sA + sB + 1e-16f);
  const float mk = mask[row];
  bf16x8 a = *(const bf16x8*)(OaccA + e);
  bf16x8 bb = *(const bf16x8*)(OaccB + e);
  bf16x8 q = *(const bf16x8*)(Qp + e);
  float r[8];
#pragma unroll
  for (int k = 0; k < 8; ++k) {
    float num = b2f((unsigned short)a[k]) + b2f((unsigned short)bb[k]);
    r[k] = b2f((unsigned short)q[k]) + mk * (num * inv);
  }
  uint4 rr;
  rr.x = cvtpk(r[0], r[1]); rr.y = cvtpk(r[2], r[3]);
  rr.z = cvtpk(r[4], r[5]); rr.w = cvtpk(r[6], r[7]);
  *(uint4*)(Obb + e) = rr;
}

// ---------------- final: out = Obb + relu((Obb@Wo + bo) * mask)
__global__ __launch_bounds__(256) void final2_kernel(
    const short* __restrict__ Obb,
    const short* __restrict__ Wto, const float* __restrict__ bo,
    const float* __restrict__ maskf, float* __restrict__ out) {
  __shared__ short Al[2 * 128 * 64];
  __shared__ short Bl[2 * 128 * 64];
  const int m0 = blockIdx.x * 128, n0 = blockIdx.y * 128;
  const int t = threadIdx.x;
  const f32x4 zz = {0.f, 0.f, 0.f, 0.f};
  f32x4 acc[4][4];
#pragma unroll
  for (int mi = 0; mi < 4; ++mi)
#pragma unroll
    for (int ni = 0; ni < 4; ++ni) acc[mi][ni] = zz;
  gemm_bf16_core(Obb, Wto + n0 * 512, Al, Bl, m0, t, acc);

  const int lane = t & 63, w = t >> 6;
  const int c = lane & 15, g = lane >> 4;
  const int wr = w >> 1, wc = w & 1;
  float mk[4][4];
#pragma unroll
  for (int mi = 0; mi < 4; ++mi) {
    int mbase = m0 + wr * 64 + mi * 16 + 4 * g;
#pragma unroll
    for (int i = 0; i < 4; ++i) mk[mi][i] = maskf[mbase + i];
  }
#pragma unroll
  for (int ni = 0; ni < 4; ++ni) {
    int n = n0 + wc * 64 + ni * 16 + c;
    float bval = bo[n];
#pragma unroll
    for (int mi = 0; mi < 4; ++mi) {
      int mbase = m0 + wr * 64 + mi * 16 + 4 * g;
#pragma unroll
      for (int i = 0; i < 4; ++i) {
        float v = (acc[mi][ni][i] + bval) * mk[mi][i];
        v = fmaxf(v, 0.f);
        size_t off = (size_t)(mbase + i) * 512 + n;
        out[off] = b2f((unsigned short)Obb[off]) + v;
      }
    }
  }
}

extern "C" void kernel_launch(void* const* d_in, const int* in_sizes, int n_in,
                              void* d_out, int out_size, void* d_ws, size_t ws_size,
                              hipStream_t stream) {
  (void)in_sizes; (void)n_in; (void)out_size; (void)ws_size;
  const float* Q    = (const float*)d_in[0];
  const float* K    = (const float*)d_in[1];
  const float* mask = (const float*)d_in[2];
  const float* Wq   = (const float*)d_in[3];
  const float* bq   = (const float*)d_in[4];
  const float* Wk   = (const float*)d_in[5];
  const float* bk   = (const float*)d_in[6];
  const float* Wv   = (const float*)d_in[7];
  const float* bv   = (const float*)d_in[8];
  const float* Wo   = (const float*)d_in[9];
  const float* bo   = (const float*)d_in[10];

  char* ws = (char*)d_ws;
  const size_t MB = 1048576;
  short* Wt4   = (short*)ws;                  // 0-2 MB: 4x 512x512 bf16
  short* Qb    = (short*)(ws + 2 * MB);       // 2-10 MB (dead after proj2)
  short* Kb    = (short*)(ws + 10 * MB);      // 10-18 MB (dead after proj2)
  short* OaccA = (short*)(ws + 2 * MB);       // aliases Qb (attn runs after proj2)
  short* OaccB = (short*)(ws + 10 * MB);      // aliases Kb
  short* Qp    = (short*)(ws + 18 * MB);      // 18-26 MB
  short* Kp    = (short*)(ws + 26 * MB);      // 26-34 MB
  short* Vt    = (short*)(ws + 34 * MB);      // 34-42 MB: [B][H][64][1024]
  short* Obb   = (short*)(ws + 42 * MB);      // 42-50 MB
  float* ml    = (float*)(ws + 50 * MB);      // 32 KB logmask
  float* saccA = (float*)(ws + 50 * MB + 262144);   // 256 KB
  float* saccB = (float*)(ws + 50 * MB + 2 * 262144); // 256 KB
  float* out   = (float*)d_out;

  wtrans_kernel<<<dim3(8, 8, 4), 256, 0, stream>>>(Wq, Wk, Wv, Wo, Wt4);
  cvt_kernel<<<dim3(2048, 2), 256, 0, stream>>>(Q, K, mask, Qb, Kb, ml);
  proj2_kernel<<<dim3(64, 12), 256, 0, stream>>>(Qb, Kb, Wt4, bq, bk, bv, mask, Qp, Kp, Vt);
  attn_split_kernel<<<dim3(2048), 256, 0, stream>>>(Qp, Kp, Vt, ml, OaccA, OaccB, saccA, saccB);
  combine_kernel<<<dim3(2048), 256, 0, stream>>>(OaccA, OaccB, saccA, saccB, Qp, mask, Obb);
  final2_kernel<<<dim3(64, 4), 256, 0, stream>>>(Obb, Wt4 + 3 * 262144, bo, mask, out);
}

// Round 8
// 88.898 us; speedup vs baseline: 2.1364x; 1.0792x over previous
//
#include <hip/hip_runtime.h>

typedef short bf16x8 __attribute__((ext_vector_type(8)));
typedef float f32x4 __attribute__((ext_vector_type(4)));

#define MFMA16(a, b, c) __builtin_amdgcn_mfma_f32_16x16x32_bf16((a), (b), (c), 0, 0, 0)

#define GLOAD_LDS16(g, l)                                              \
  __builtin_amdgcn_global_load_lds(                                    \
      (const __attribute__((address_space(1))) unsigned int*)(g),      \
      (__attribute__((address_space(3))) unsigned int*)(l), 16, 0, 0)

__device__ __forceinline__ unsigned short f2b(float f) {
  union { float f; unsigned int u; } x; x.f = f;
  unsigned int r = x.u + 0x7FFFu + ((x.u >> 16) & 1u);
  return (unsigned short)(r >> 16);
}
__device__ __forceinline__ float b2f(unsigned short h) {
  union { unsigned int u; float f; } x; x.u = ((unsigned int)h) << 16;
  return x.f;
}
__device__ __forceinline__ unsigned int cvtpk(float lo, float hi) {
  unsigned int r;
  asm("v_cvt_pk_bf16_f32 %0, %1, %2" : "=v"(r) : "v"(lo), "v"(hi));
  return r;
}
__device__ __forceinline__ short cvt1(float x) {
  return (short)(unsigned short)cvtpk(x, x);
}
__device__ __forceinline__ float vexp2(float x) {  // raw v_exp_f32 (base-2)
  float r;
  asm("v_exp_f32 %0, %1" : "=v"(r) : "v"(x));
  return r;
}

// ---------------- weight transpose+convert: W[512][512] f32 -> Wt[512n][512k] bf16
__global__ __launch_bounds__(256) void wtrans_kernel(
    const float* __restrict__ Wq, const float* __restrict__ Wk,
    const float* __restrict__ Wv, const float* __restrict__ Wo,
    short* __restrict__ Wt) {
  __shared__ float tile[64][65];
  const int z = blockIdx.z;
  const float* W = (z == 0) ? Wq : (z == 1) ? Wk : (z == 2) ? Wv : Wo;
  const int k0 = blockIdx.x * 64, n0 = blockIdx.y * 64;
  const int t = threadIdx.x;
  const int r = t >> 4, cc = (t & 15) * 4;
#pragma unroll
  for (int it = 0; it < 4; ++it) {
    int row = r + it * 16;
    const float4 v = *(const float4*)(W + (k0 + row) * 512 + n0 + cc);
    tile[row][cc + 0] = v.x; tile[row][cc + 1] = v.y;
    tile[row][cc + 2] = v.z; tile[row][cc + 3] = v.w;
  }
  __syncthreads();
  short* out = Wt + z * (512 * 512);
#pragma unroll
  for (int it = 0; it < 4; ++it) {
    int nrow = r + it * 16;
    unsigned int u0 = cvtpk(tile[cc + 0][nrow], tile[cc + 1][nrow]);
    unsigned int u1 = cvtpk(tile[cc + 2][nrow], tile[cc + 3][nrow]);
    uint2 uv; uv.x = u0; uv.y = u1;
    *(uint2*)(out + (n0 + nrow) * 512 + k0 + cc) = uv;
  }
}

// ---------------- convert Q,K f32 -> bf16; also build additive logmask ml
__global__ __launch_bounds__(256) void cvt_kernel(
    const float* __restrict__ Q, const float* __restrict__ K,
    const float* __restrict__ mask,
    short* __restrict__ Qb, short* __restrict__ Kb, float* __restrict__ ml) {
  if (blockIdx.y == 0 && blockIdx.x < 4) {
    int i = (blockIdx.x * 256 + threadIdx.x) * 8;
    float4 a = *(const float4*)(mask + i);
    float4 bb = *(const float4*)(mask + i + 4);
    float4 ra, rb;
    ra.x = (a.x != 0.f) ? 0.f : -1e30f;
    ra.y = (a.y != 0.f) ? 0.f : -1e30f;
    ra.z = (a.z != 0.f) ? 0.f : -1e30f;
    ra.w = (a.w != 0.f) ? 0.f : -1e30f;
    rb.x = (bb.x != 0.f) ? 0.f : -1e30f;
    rb.y = (bb.y != 0.f) ? 0.f : -1e30f;
    rb.z = (bb.z != 0.f) ? 0.f : -1e30f;
    rb.w = (bb.w != 0.f) ? 0.f : -1e30f;
    *(float4*)(ml + i) = ra;
    *(float4*)(ml + i + 4) = rb;
  }
  const float* src = blockIdx.y ? K : Q;
  short* dst = blockIdx.y ? Kb : Qb;
  int i = (blockIdx.x * 256 + threadIdx.x) * 8;
  float4 v0 = *(const float4*)(src + i);
  float4 v1 = *(const float4*)(src + i + 4);
  uint2 a, b;
  a.x = cvtpk(v0.x, v0.y); a.y = cvtpk(v0.z, v0.w);
  b.x = cvtpk(v1.x, v1.y); b.y = cvtpk(v1.z, v1.w);
  *(uint2*)(dst + i) = a;
  *(uint2*)(dst + i + 4) = b;
}

// ---------------- GEMM mainloop: 128x128 tile, BK=64, single-buffer LDS (32KB) + T2 swizzle
// Lb = 16384 shorts: Al = Lb[0..8192), Bl = Lb[8192..16384)
__device__ __forceinline__ void gemm_bf16_core(
    const short* __restrict__ A, const short* __restrict__ Wt,
    short* Lb, int m0, int t, f32x4 acc[4][4]) {
  const int lane = t & 63, w = t >> 6;
  const int c = lane & 15, g = lane >> 4;
  const int wr = w >> 1, wc = w & 1;
  const int lr = lane >> 3;
  const int sswz = ((lane & 7) ^ lr) << 3;  // pre-swizzled source slot (shorts)
  const int swc = (c & 7) << 3;             // read-side XOR key (shorts)
  short* Al = Lb;
  short* Bl = Lb + 8192;

  for (int kt = 0; kt < 8; ++kt) {
#pragma unroll
    for (int it = 0; it < 4; ++it) {
      int row = w * 32 + it * 8;
      GLOAD_LDS16(A + (size_t)(m0 + row + lr) * 512 + kt * 64 + sswz, Al + row * 64);
      GLOAD_LDS16(Wt + (size_t)(row + lr) * 512 + kt * 64 + sswz, Bl + row * 64);
    }
    __syncthreads();
    __builtin_amdgcn_s_setprio(1);
#pragma unroll
    for (int kc = 0; kc < 2; ++kc) {
      bf16x8 af[4], bfr[4];
#pragma unroll
      for (int mi = 0; mi < 4; ++mi) {
        int r = wr * 64 + mi * 16 + c;
        af[mi] = *(const bf16x8*)(Al + r * 64 + ((kc * 32 + 8 * g) ^ swc));
      }
#pragma unroll
      for (int ni = 0; ni < 4; ++ni) {
        int r = wc * 64 + ni * 16 + c;
        bfr[ni] = *(const bf16x8*)(Bl + r * 64 + ((kc * 32 + 8 * g) ^ swc));
      }
#pragma unroll
      for (int mi = 0; mi < 4; ++mi)
#pragma unroll
        for (int ni = 0; ni < 4; ++ni)
          acc[mi][ni] = MFMA16(af[mi], bfr[ni], acc[mi][ni]);
    }
    __builtin_amdgcn_s_setprio(0);
    __syncthreads();
  }
}

// ---------------- fused projections (LDS-transpose epilogue, coalesced stores)
__global__ __launch_bounds__(256) void proj2_kernel(
    const short* __restrict__ Qb, const short* __restrict__ Kb,
    const short* __restrict__ Wt4,
    const float* __restrict__ bq, const float* __restrict__ bk, const float* __restrict__ bv,
    const float* __restrict__ maskf,
    short* __restrict__ Qp, short* __restrict__ Kp, short* __restrict__ Vt) {
  __shared__ short Lbuf[16384];  // 32 KB: GEMM staging, then output transpose
  const int by = blockIdx.y;
  const int m0 = blockIdx.x * 128;
  const int t = threadIdx.x;
  const short* A;
  const short* Wt;
  const float* bias;
  int nbase;
  if (by < 4) { A = Qb; nbase = by * 128; Wt = Wt4 + nbase * 512; bias = bq; }
  else if (by < 8) { A = Kb; nbase = (by - 4) * 128; Wt = Wt4 + 262144 + nbase * 512; bias = bk; }
  else { A = Kb; nbase = (by - 8) * 128; Wt = Wt4 + 524288 + nbase * 512; bias = bv; }

  const f32x4 zz = {0.f, 0.f, 0.f, 0.f};
  f32x4 acc[4][4];
#pragma unroll
  for (int mi = 0; mi < 4; ++mi)
#pragma unroll
    for (int ni = 0; ni < 4; ++ni) acc[mi][ni] = zz;
  gemm_bf16_core(A, Wt, Lbuf, m0, t, acc);

  const int lane = t & 63, w = t >> 6;
  const int c = lane & 15, g = lane >> 4;
  const int wr = w >> 1, wc = w & 1;
  float mk[4][4];
#pragma unroll
  for (int mi = 0; mi < 4; ++mi) {
    int mbase = m0 + wr * 64 + mi * 16 + 4 * g;
#pragma unroll
    for (int i = 0; i < 4; ++i) mk[mi][i] = maskf[mbase + i];
  }
  float bval[4];
#pragma unroll
  for (int ni = 0; ni < 4; ++ni) bval[ni] = bias[nbase + wc * 64 + ni * 16 + c];

  if (by < 8) {
    // Lbuf[m][n ^ ((m&7)<<3)] b16 writes, then coalesced b128 row stores
#pragma unroll
    for (int ni = 0; ni < 4; ++ni) {
      int nloc = wc * 64 + ni * 16 + c;
#pragma unroll
      for (int mi = 0; mi < 4; ++mi) {
#pragma unroll
        for (int i = 0; i < 4; ++i) {
          int mloc = wr * 64 + mi * 16 + 4 * g + i;
          float v = (acc[mi][ni][i] + bval[ni]) * mk[mi][i];
          Lbuf[mloc * 128 + (nloc ^ ((mloc & 7) << 3))] = cvt1(v);
        }
      }
    }
    __syncthreads();
    short* outp = (by < 4) ? Qp : Kp;
    const int rrow = t >> 4, rcol = (t & 15) * 8;
#pragma unroll
    for (int p = 0; p < 8; ++p) {
      int m = p * 16 + rrow;
      bf16x8 vv = *(const bf16x8*)(Lbuf + m * 128 + (rcol ^ ((m & 7) << 3)));
      *(bf16x8*)(outp + (size_t)(m0 + m) * 512 + nbase + rcol) = vv;
    }
  } else {
    // Vt: transposed Lbuf[n][m-chunk16 ^ (n&7)] b64 writes, then coalesced b128 stores
#pragma unroll
    for (int ni = 0; ni < 4; ++ni) {
      int nloc = wc * 64 + ni * 16 + c;
#pragma unroll
      for (int mi = 0; mi < 4; ++mi) {
        int mloc4 = wr * 64 + mi * 16 + 4 * g;
        unsigned int lo = cvtpk((acc[mi][ni][0] + bval[ni]) * mk[mi][0],
                                (acc[mi][ni][1] + bval[ni]) * mk[mi][1]);
        unsigned int hi = cvtpk((acc[mi][ni][2] + bval[ni]) * mk[mi][2],
                                (acc[mi][ni][3] + bval[ni]) * mk[mi][3]);
        int ma = (mloc4 & 15) + (((mloc4 >> 4) ^ (nloc & 7)) << 4);
        uint2 uv; uv.x = lo; uv.y = hi;
        *(uint2*)(Lbuf + nloc * 128 + ma) = uv;
      }
    }
    __syncthreads();
    const int rrow = t >> 4, rcol = (t & 15) * 8;
#pragma unroll
    for (int p = 0; p < 8; ++p) {
      int n = p * 16 + rrow;
      int ma = (rcol & 8) + (((rcol >> 4) ^ (n & 7)) << 4);
      bf16x8 vv = *(const bf16x8*)(Lbuf + n * 128 + ma);
      int d = nbase + n;
      int hh = d >> 6, dd = d & 63;
      int mg = m0 + rcol;
      int bi = mg >> 10, seq0 = mg & 1023;
      *(bf16x8*)(Vt + ((size_t)((bi * 8 + hh) * 64 + dd)) * 1024 + seq0) = vv;
    }
  }
}

// ---------------- flash attention: 2 waves x 32 q-rows, no-max softmax, raw v_exp
__global__ __launch_bounds__(128) void attn3_kernel(
    const short* __restrict__ Qp, const short* __restrict__ Kp,
    const short* __restrict__ Vt, const float* __restrict__ mask,
    const float* __restrict__ ml, short* __restrict__ Obb) {
  __shared__ short Kl[64][64];        // 8 KB, XOR-swizzled
  __shared__ short Vl[64][64];        // 8 KB
  __shared__ short Pl[2][2][16][64];  // 8 KB: [wave][grp][q16][kv]
  __shared__ float Mlds[1024];        // 4 KB logmask row
  const int t = threadIdx.x, lane = t & 63, w = t >> 6;  // w in {0,1}
  const int c = lane & 15, g = lane >> 4;
  const int hw = blockIdx.x;
  const int L = (hw & 7) * 128 + (hw >> 3);  // XCD swizzle: 8 heads per XCD
  const int qt = L & 15, hb = L >> 4;
  const int b = hb & 7, h = hb >> 3;
  const int n0 = qt * 64;
  const float scale2 = 0.06375870724f;  // log2(e)/sqrt(512)

  const short* Kg = Kp + (size_t)(b * 1024) * 512 + h * 64;
  const short* Vg = Vt + (size_t)((b * 8 + h) * 64) * 1024;
  const float* Lg = ml + b * 1024;
  const int sswz = ((lane & 7) ^ (lane >> 3)) << 3;
  const int swc = (c & 7) << 3;

  bf16x8 qf[2][2];
#pragma unroll
  for (int grp = 0; grp < 2; ++grp) {
    const short* qptr = Qp + ((size_t)(b * 1024 + n0 + w * 32 + grp * 16 + c) * 512 + h * 64 + 8 * g);
    qf[grp][0] = *(const bf16x8*)qptr;
    qf[grp][1] = *(const bf16x8*)(qptr + 32);
  }
  bf16x8 ones;
#pragma unroll
  for (int k = 0; k < 8; ++k) ones[k] = (short)0x3F80;  // bf16 1.0

  auto STAGEKV = [&](int kvt) {
    const int kr = kvt * 64;
#pragma unroll
    for (int it = 0; it < 4; ++it) {
      int row = it * 16 + w * 8;  // wave-uniform base row
      GLOAD_LDS16(Kg + (size_t)(kr + row + (lane >> 3)) * 512 + sswz, &Kl[row][0]);
      GLOAD_LDS16(Vg + (size_t)(row + (lane >> 3)) * 1024 + kr + sswz, &Vl[row][0]);
    }
  };

  // prologue: logmask + tile 0
  GLOAD_LDS16(Lg + w * 512 + lane * 4, &Mlds[w * 512]);
  GLOAD_LDS16(Lg + w * 512 + 256 + lane * 4, &Mlds[w * 512 + 256]);
  STAGEKV(0);
  __syncthreads();

  const f32x4 zz = {0.f, 0.f, 0.f, 0.f};
  f32x4 o[2][4];
  f32x4 suma[2];
#pragma unroll
  for (int grp = 0; grp < 2; ++grp) {
    suma[grp] = zz;
#pragma unroll
    for (int nb = 0; nb < 4; ++nb) o[grp][nb] = zz;
  }

#pragma unroll 1
  for (int kvt = 0; kvt < 16; ++kvt) {
    float4 lm[4];
#pragma unroll
    for (int j = 0; j < 4; ++j)
      lm[j] = *(const float4*)(&Mlds[kvt * 64 + 16 * j + 4 * g]);

    // QK^T swapped (K-frags shared across both q-groups)
    f32x4 sv[2][4];
    __builtin_amdgcn_s_setprio(1);
#pragma unroll
    for (int j = 0; j < 4; ++j) {
      bf16x8 af0 = *(const bf16x8*)(&Kl[16 * j + c][(8 * g) ^ swc]);
      bf16x8 af1 = *(const bf16x8*)(&Kl[16 * j + c][(32 + 8 * g) ^ swc]);
#pragma unroll
      for (int grp = 0; grp < 2; ++grp) {
        f32x4 sj = MFMA16(af0, qf[grp][0], zz);
        sv[grp][j] = MFMA16(af1, qf[grp][1], sj);
      }
    }
    __builtin_amdgcn_s_setprio(0);

    // numerator p = exp2(scale2*s + lm) via raw v_exp_f32
#pragma unroll
    for (int grp = 0; grp < 2; ++grp) {
#pragma unroll
      for (int j = 0; j < 4; ++j) {
        float p0 = vexp2(fmaf(scale2, sv[grp][j][0], lm[j].x));
        float p1 = vexp2(fmaf(scale2, sv[grp][j][1], lm[j].y));
        float p2 = vexp2(fmaf(scale2, sv[grp][j][2], lm[j].z));
        float p3 = vexp2(fmaf(scale2, sv[grp][j][3], lm[j].w));
        uint2 pw; pw.x = cvtpk(p0, p1); pw.y = cvtpk(p2, p3);
        *(uint2*)(&Pl[w][grp][c][(16 * j + 4 * g) ^ swc]) = pw;
      }
    }

    // PV + rowsum (V-frags shared across q-groups)
    __builtin_amdgcn_s_setprio(1);
#pragma unroll
    for (int ks = 0; ks < 2; ++ks) {
      bf16x8 vb[4];
#pragma unroll
      for (int nb = 0; nb < 4; ++nb)
        vb[nb] = *(const bf16x8*)(&Vl[16 * nb + c][(ks * 32 + 8 * g) ^ swc]);
#pragma unroll
      for (int grp = 0; grp < 2; ++grp) {
        bf16x8 pa = *(const bf16x8*)(&Pl[w][grp][c][(ks * 32 + 8 * g) ^ swc]);
        suma[grp] = MFMA16(pa, ones, suma[grp]);
#pragma unroll
        for (int nb = 0; nb < 4; ++nb)
          o[grp][nb] = MFMA16(pa, vb[nb], o[grp][nb]);
      }
    }
    __builtin_amdgcn_s_setprio(0);

    if (kvt < 15) {
      __syncthreads();
      STAGEKV(kvt + 1);
      __syncthreads();
    }
  }

  // epilogue: normalize, add q-residual, mask, write bf16
#pragma unroll
  for (int grp = 0; grp < 2; ++grp) {
    float inv[4], mk1[4];
#pragma unroll
    for (int i = 0; i < 4; ++i) {
      inv[i] = __builtin_amdgcn_rcpf(suma[grp][i] + 1e-16f);
      mk1[i] = mask[b * 1024 + n0 + w * 32 + grp * 16 + 4 * g + i];
    }
#pragma unroll
    for (int nb = 0; nb < 4; ++nb) {
      int colg = h * 64 + 16 * nb + c;
#pragma unroll
      for (int i = 0; i < 4; ++i) {
        int row = n0 + w * 32 + grp * 16 + 4 * g + i;
        float att = o[grp][nb][i] * inv[i];
        float qv = b2f(*(const unsigned short*)(Qp + (size_t)(b * 1024 + row) * 512 + colg));
        float res = qv + mk1[i] * att;
        Obb[(size_t)(b * 1024 + row) * 512 + colg] = cvt1(res);
      }
    }
  }
}

// ---------------- final: out = Obb + relu((Obb@Wo + bo) * mask)   (f32 stores = full lines)
__global__ __launch_bounds__(256) void final2_kernel(
    const short* __restrict__ Obb,
    const short* __restrict__ Wto, const float* __restrict__ bo,
    const float* __restrict__ maskf, float* __restrict__ out) {
  __shared__ short Lbuf[16384];
  const int m0 = blockIdx.x * 128, n0 = blockIdx.y * 128;
  const int t = threadIdx.x;
  const f32x4 zz = {0.f, 0.f, 0.f, 0.f};
  f32x4 acc[4][4];
#pragma unroll
  for (int mi = 0; mi < 4; ++mi)
#pragma unroll
    for (int ni = 0; ni < 4; ++ni) acc[mi][ni] = zz;
  gemm_bf16_core(Obb, Wto + n0 * 512, Lbuf, m0, t, acc);

  const int lane = t & 63, w = t >> 6;
  const int c = lane & 15, g = lane >> 4;
  const int wr = w >> 1, wc = w & 1;
  float mk[4][4];
#pragma unroll
  for (int mi = 0; mi < 4; ++mi) {
    int mbase = m0 + wr * 64 + mi * 16 + 4 * g;
#pragma unroll
    for (int i = 0; i < 4; ++i) mk[mi][i] = maskf[mbase + i];
  }
#pragma unroll
  for (int ni = 0; ni < 4; ++ni) {
    int n = n0 + wc * 64 + ni * 16 + c;
    float bval = bo[n];
#pragma unroll
    for (int mi = 0; mi < 4; ++mi) {
      int mbase = m0 + wr * 64 + mi * 16 + 4 * g;
#pragma unroll
      for (int i = 0; i < 4; ++i) {
        float v = (acc[mi][ni][i] + bval) * mk[mi][i];
        v = fmaxf(v, 0.f);
        size_t off = (size_t)(mbase + i) * 512 + n;
        out[off] = b2f((unsigned short)Obb[off]) + v;
      }
    }
  }
}

extern "C" void kernel_launch(void* const* d_in, const int* in_sizes, int n_in,
                              void* d_out, int out_size, void* d_ws, size_t ws_size,
                              hipStream_t stream) {
  (void)in_sizes; (void)n_in; (void)out_size; (void)ws_size;
  const float* Q    = (const float*)d_in[0];
  const float* K    = (const float*)d_in[1];
  const float* mask = (const float*)d_in[2];
  const float* Wq   = (const float*)d_in[3];
  const float* bq   = (const float*)d_in[4];
  const float* Wk   = (const float*)d_in[5];
  const float* bk   = (const float*)d_in[6];
  const float* Wv   = (const float*)d_in[7];
  const float* bv   = (const float*)d_in[8];
  const float* Wo   = (const float*)d_in[9];
  const float* bo   = (const float*)d_in[10];

  char* ws = (char*)d_ws;
  const size_t MB = 1048576;
  short* Wt4 = (short*)ws;                 // 0-2 MB: 4x 512x512 bf16
  short* Qb  = (short*)(ws + 2 * MB);      // 2-10 MB (dead after proj2)
  short* Kb  = (short*)(ws + 10 * MB);     // 10-18 MB (dead after proj2)
  short* Qp  = (short*)(ws + 18 * MB);     // 18-26 MB
  short* Kp  = (short*)(ws + 26 * MB);     // 26-34 MB
  short* Vt  = (short*)(ws + 34 * MB);     // 34-42 MB: [B][H][64][1024]
  short* Obb = (short*)(ws + 42 * MB);     // 42-50 MB
  float* ml  = (float*)(ws + 50 * MB);     // 32 KB logmask
  float* out = (float*)d_out;

  wtrans_kernel<<<dim3(8, 8, 4), 256, 0, stream>>>(Wq, Wk, Wv, Wo, Wt4);
  cvt_kernel<<<dim3(2048, 2), 256, 0, stream>>>(Q, K, mask, Qb, Kb, ml);
  proj2_kernel<<<dim3(64, 12), 256, 0, stream>>>(Qb, Kb, Wt4, bq, bk, bv, mask, Qp, Kp, Vt);
  attn3_kernel<<<dim3(1024), 128, 0, stream>>>(Qp, Kp, Vt, mask, ml, Obb);
  final2_kernel<<<dim3(64, 4), 256, 0, stream>>>(Obb, Wt4 + 3 * 262144, bo, mask, out);
}